// Round 10
// baseline (2517.954 us; speedup 1.0000x reference)
//
#include <hip/hip_runtime.h>
#include <math.h>

// ---------------------------------------------------------------------------
// HAGMoE — round 10 (= R9 with compile fix): fuse A-fold into scores (fsc_k).
// BIG3 (402 MB write + 402 MB read) eliminated: per block (b,mod), A64 tiles
// are computed on the fly from QALL (64 KB/block, register-hoisted fragments)
// and wT3 (L2/L3-resident), split hi/lo into LDS, then consumed by the scores
// MFMA against staged h_sent. Numerics bit-identical to R8 (split-bf16 3-MFMA
// everywhere pre-routing; single-bf16 post-routing only).
// Also: glog/elog/cls tiny-N GEMMs -> per-wave dot kernels.
// ---------------------------------------------------------------------------

#define B_    256
#define S_    256
#define T_    16
#define H_    1024
#define NH_   8
#define DH_   128
#define M128_ 128
#define G_    3
#define E_    8
#define I_    4096
#define R_    256
#define L_    3
#define GE_   24

using bf16x8 = __attribute__((ext_vector_type(8))) __bf16;
using f32x4  = __attribute__((ext_vector_type(4))) float;

__device__ inline float wave_sum(float v) {
    for (int o = 32; o > 0; o >>= 1) v += __shfl_xor(v, o);
    return v;
}
__device__ inline float wave_max(float v) {
    for (int o = 32; o > 0; o >>= 1) v = fmaxf(v, __shfl_xor(v, o));
    return v;
}

__device__ inline void split8(const float4& f0, const float4& f1, bf16x8& hi, bf16x8& lo)
{
    const float fv[8] = {f0.x, f0.y, f0.z, f0.w, f1.x, f1.y, f1.z, f1.w};
#pragma unroll
    for (int j = 0; j < 8; ++j) {
        const __bf16 h = (__bf16)fv[j];
        hi[j] = h; lo[j] = (__bf16)(fv[j] - (float)h);
    }
}

// ===================== FUSED A-fold + scores =====================
// grid (1,1,1024); zz = ((z&7)<<7)|(z>>3); b = zz>>2, mod = zz&3 (mod==3 exits).
// SC3[mod][b][m=t*8+h][s] = rscale*(sum_k A64[m][k]*h_sent[b][s][k] + OFFS3[mod][b][m])
// A64[m][k] = sum_j QALL[b][t][mod*1024+h*128+j] * wT3[mod][k*1024+h*128+j]
__global__ __launch_bounds__(512) void fsc_k(
    const float* __restrict__ QALL, const float* __restrict__ wT3,
    const float* __restrict__ hs, const float* __restrict__ OFFS3,
    float* __restrict__ SC3, float rscale)
{
    const int zz = ((blockIdx.z & 7) << 7) | (blockIdx.z >> 3);
    const int b = zz >> 2, mod = zz & 3;
    if (mod == 3) return;

    __shared__ __bf16 A64h[128 * 72];
    __shared__ __bf16 A64l[128 * 72];
    __shared__ __bf16 Bh[128 * 40];
    __shared__ __bf16 Bl[128 * 40];

    const int tid  = threadIdx.x;
    const int lane = tid & 63;
    const int wid  = tid >> 6;          // 0..7 = head in phase1
    const int fr   = lane & 15;
    const int fk   = lane >> 4;         // 0..3
    const int wm2  = (wid >> 2) * 64;   // phase2 row block
    const int wn2  = (wid & 3) * 32;    // phase2 col block (within 128-half)

    // ---- hoist Q fragments (phase1 A-operand): row t=fr, head wid ----
    bf16x8 qh[4], ql[4];
    {
        const float* qb = QALL + ((long)(b * 16 + fr)) * 4096 + mod * 1024 + wid * 128;
#pragma unroll
        for (int jc = 0; jc < 4; ++jc) {
            const float* p = qb + jc * 32 + fk * 8;
            split8(*(const float4*)p, *(const float4*)(p + 4), qh[jc], ql[jc]);
        }
    }

    f32x4 acc[2][4][2] = {};
    const float* wbase = wT3 + (long)mod * 1048576 + wid * 128;
    const float* hb = hs + (long)b * 262144;

    for (int ks = 0; ks < 16; ++ks) {
        __syncthreads();   // previous phase2 done reading A64
        // ---- phase1: A64[:, ks*64 .. +64) ----
#pragma unroll
        for (int nt = 0; nt < 4; ++nt) {
            f32x4 pa = {};
            const float* wr = wbase + (long)(ks * 64 + nt * 16 + fr) * 1024;
#pragma unroll
            for (int jc = 0; jc < 4; ++jc) {
                const float* p = wr + jc * 32 + fk * 8;
                bf16x8 wh, wl;
                split8(*(const float4*)p, *(const float4*)(p + 4), wh, wl);
                pa = __builtin_amdgcn_mfma_f32_16x16x32_bf16(qh[jc], wh, pa, 0, 0, 0);
                pa = __builtin_amdgcn_mfma_f32_16x16x32_bf16(qh[jc], wl, pa, 0, 0, 0);
                pa = __builtin_amdgcn_mfma_f32_16x16x32_bf16(ql[jc], wh, pa, 0, 0, 0);
            }
            const int kl = nt * 16 + fr;   // C/D col = lane&15
#pragma unroll
            for (int r = 0; r < 4; ++r) {  // C/D row = (lane>>4)*4 + r = t
                const int m = (fk * 4 + r) * 8 + wid;
                const float v = pa[r];
                const __bf16 hv = (__bf16)v;
                A64h[m * 72 + kl] = hv;
                A64l[m * 72 + kl] = (__bf16)(v - (float)hv);
            }
        }
        // ---- phase2: acc += A64 @ h_sent_chunk ----
#pragma unroll 1
        for (int half = 0; half < 2; ++half) {
#pragma unroll 1
            for (int kc = 0; kc < 2; ++kc) {
                __syncthreads();   // Bh free (also: A64 ready on first pass)
                {
                    const int r2 = tid >> 2, q2 = tid & 3;
                    const float* p = hb + (long)(half * 128 + r2) * 1024 +
                                     ks * 64 + kc * 32 + q2 * 8;
                    bf16x8 hh, hl;
                    split8(*(const float4*)p, *(const float4*)(p + 4), hh, hl);
                    *(bf16x8*)&Bh[r2 * 40 + q2 * 8] = hh;
                    *(bf16x8*)&Bl[r2 * 40 + q2 * 8] = hl;
                }
                __syncthreads();
                const int klo = kc * 32 + fk * 8;
#pragma unroll
                for (int mt = 0; mt < 4; ++mt) {
                    const bf16x8 ah = *(const bf16x8*)&A64h[(wm2 + mt * 16 + fr) * 72 + klo];
                    const bf16x8 al = *(const bf16x8*)&A64l[(wm2 + mt * 16 + fr) * 72 + klo];
#pragma unroll
                    for (int nt = 0; nt < 2; ++nt) {
                        const bf16x8 bh = *(const bf16x8*)&Bh[(wn2 + nt * 16 + fr) * 40 + fk * 8];
                        const bf16x8 bl = *(const bf16x8*)&Bl[(wn2 + nt * 16 + fr) * 40 + fk * 8];
                        acc[half][mt][nt] = __builtin_amdgcn_mfma_f32_16x16x32_bf16(ah, bh, acc[half][mt][nt], 0, 0, 0);
                        acc[half][mt][nt] = __builtin_amdgcn_mfma_f32_16x16x32_bf16(ah, bl, acc[half][mt][nt], 0, 0, 0);
                        acc[half][mt][nt] = __builtin_amdgcn_mfma_f32_16x16x32_bf16(al, bh, acc[half][mt][nt], 0, 0, 0);
                    }
                }
            }
        }
    }

    // ---- epilogue ----
    float* out = SC3 + (long)mod * 8388608 + (long)b * 32768;
    const float* ro = OFFS3 + mod * 32768 + b * 128;
    const int lr4 = fk * 4;
#pragma unroll
    for (int half = 0; half < 2; ++half)
#pragma unroll
        for (int mt = 0; mt < 4; ++mt)
#pragma unroll
            for (int r = 0; r < 4; ++r) {
                const int rr = wm2 + mt * 16 + lr4 + r;
                const float rov = ro[rr];
#pragma unroll
                for (int nt = 0; nt < 2; ++nt) {
                    const int cc = half * 128 + wn2 + nt * 16 + fr;
                    out[(long)rr * 256 + cc] = (acc[half][mt][nt][r] + rov) * rscale;
                }
            }
}

// ===================== split-bf16 MFMA GEMM, 128x128, prefetched =============
template <int ACT>
__global__ __launch_bounds__(256) void sgemm2_k(
    const float* __restrict__ Ap, const float* __restrict__ Bp,
    const float* __restrict__ biasp, const float* __restrict__ roffp,
    float* __restrict__ Cf,
    int K, int m2shift, int zshift,
    long sA1, long sA2, long sAz1, long sAz2,
    long ldb, long sBz1, long sBz2, long sBia1, long sBia2,
    long sC1, long sC2, long sCz1, long sCz2, long sR1, long sR2,
    float scale)
{
    const int z  = blockIdx.z;
    const int z1 = z >> zshift;
    const int z2 = z & ((1 << zshift) - 1);
    const int m2mask = (1 << m2shift) - 1;
    const int row0 = blockIdx.y * 128;
    const int col0 = blockIdx.x * 128;
    const float* Ab = Ap + (long)z1 * sAz1 + (long)z2 * sAz2;
    const float* Bb = Bp + (long)z1 * sBz1 + (long)z2 * sBz2;
    const float* biasb = biasp ? biasp + (long)z1 * sBia1 + (long)z2 * sBia2 : nullptr;
    const float* roffb = roffp ? roffp + (long)z1 * sR1 + (long)z2 * sR2 : nullptr;

    __shared__ __bf16 Ahs[128 * 40];
    __shared__ __bf16 Als[128 * 40];
    __shared__ __bf16 Bhs[128 * 40];
    __shared__ __bf16 Bls[128 * 40];

    const int tid  = threadIdx.x;
    const int lane = tid & 63;
    const int wid  = tid >> 6;
    const int wm = (wid >> 1) * 64;
    const int wn = (wid & 1) * 64;
    const int fr  = lane & 15;
    const int fkb = (lane >> 4) * 16;
    const int qrow = tid >> 2;
    const int c4   = tid & 3;

    f32x4 acc[4][4] = {};
    float4 pfa[2][2], pfb[2][2];

    auto loadAB = [&](int k0) {
#pragma unroll
        for (int rep = 0; rep < 2; ++rep) {
            const int row = qrow + rep * 64;
            const int r = row0 + row;
            const int r1 = r >> m2shift, r2 = r & m2mask;
            const float* srcA = Ab + (long)r1 * sA1 + (long)r2 * sA2 + k0 + c4 * 8;
            pfa[rep][0] = *(const float4*)srcA;
            pfa[rep][1] = *(const float4*)(srcA + 4);
            const float* srcB = Bb + (long)(col0 + row) * ldb + k0 + c4 * 8;
            pfb[rep][0] = *(const float4*)srcB;
            pfb[rep][1] = *(const float4*)(srcB + 4);
        }
    };

    loadAB(0);
    for (int k0 = 0; k0 < K; k0 += 32) {
        __syncthreads();
#pragma unroll
        for (int rep = 0; rep < 2; ++rep) {
            const int row = qrow + rep * 64;
            bf16x8 hi, lo;
            split8(pfa[rep][0], pfa[rep][1], hi, lo);
            *(bf16x8*)&Ahs[row * 40 + c4 * 8] = hi;
            *(bf16x8*)&Als[row * 40 + c4 * 8] = lo;
            split8(pfb[rep][0], pfb[rep][1], hi, lo);
            *(bf16x8*)&Bhs[row * 40 + c4 * 8] = hi;
            *(bf16x8*)&Bls[row * 40 + c4 * 8] = lo;
        }
        __syncthreads();
        if (k0 + 32 < K) loadAB(k0 + 32);

        bf16x8 bh4[4], bl4[4];
#pragma unroll
        for (int n = 0; n < 4; ++n) {
            bh4[n] = *(const bf16x8*)((const char*)&Bhs[(wn + n * 16 + fr) * 40] + fkb);
            bl4[n] = *(const bf16x8*)((const char*)&Bls[(wn + n * 16 + fr) * 40] + fkb);
        }
#pragma unroll
        for (int m = 0; m < 4; ++m) {
            const bf16x8 ah = *(const bf16x8*)((const char*)&Ahs[(wm + m * 16 + fr) * 40] + fkb);
            const bf16x8 al = *(const bf16x8*)((const char*)&Als[(wm + m * 16 + fr) * 40] + fkb);
#pragma unroll
            for (int n = 0; n < 4; ++n) {
                acc[m][n] = __builtin_amdgcn_mfma_f32_16x16x32_bf16(ah, bh4[n], acc[m][n], 0, 0, 0);
                acc[m][n] = __builtin_amdgcn_mfma_f32_16x16x32_bf16(ah, bl4[n], acc[m][n], 0, 0, 0);
                acc[m][n] = __builtin_amdgcn_mfma_f32_16x16x32_bf16(al, bh4[n], acc[m][n], 0, 0, 0);
            }
        }
    }

    float* Cfb = Cf + (long)z1 * sCz1 + (long)z2 * sCz2;
    const int lr4 = (lane >> 4) * 4;
#pragma unroll
    for (int m = 0; m < 4; ++m) {
#pragma unroll
        for (int r = 0; r < 4; ++r) {
            const int rr = row0 + wm + m * 16 + lr4 + r;
            const int r1 = rr >> m2shift, r2 = rr & m2mask;
            const float ro = roffb ? roffb[rr] : 0.f;
            const long cb = (long)r1 * sC1 + (long)r2 * sC2;
#pragma unroll
            for (int n = 0; n < 4; ++n) {
                const int cc = col0 + wn + n * 16 + fr;
                float v = (acc[m][n][r] + ro) * scale;
                if (biasp) v += biasb[cc];
                if (ACT == 2) v = 1.0f / (1.0f + expf(-v));
                Cfb[cb + cc] = v;
            }
        }
    }
}

static void sg2(hipStream_t s, int act,
                const float* A, const float* B, const float* bias, const float* roff,
                float* C, int gx, int gy, int gz,
                int K, int m2shift, int zshift,
                long sA1, long sA2, long sAz1, long sAz2,
                long ldb, long sBz1, long sBz2, long sBia1, long sBia2,
                long sC1, long sC2, long sCz1, long sCz2, long sR1, long sR2,
                float scale)
{
    dim3 g(gx, gy, gz), b(256);
#define S2ARGS A, B, bias, roff, C, K, m2shift, zshift, sA1, sA2, sAz1, sAz2, \
               ldb, sBz1, sBz2, sBia1, sBia2, sC1, sC2, sCz1, sCz2, sR1, sR2, scale
    if (act == 2) sgemm2_k<2><<<g, b, 0, s>>>(S2ARGS);
    else          sgemm2_k<0><<<g, b, 0, s>>>(S2ARGS);
#undef S2ARGS
}

// ===================== 256x128 MFMA GEMM (MoE), prefetched =====================
template <int ABF16, int BSING, int ACT, int WMUL, int OUTH>
__global__ __launch_bounds__(512) void sgemm256_k(
    const void* __restrict__ Ap, const float* __restrict__ Bp,
    const float* __restrict__ biasp, const float* __restrict__ wmulp,
    float* __restrict__ Cf, __bf16* __restrict__ Ch,
    int K, long sA1, long sAz, long ldb, long sBz, long sBz2, int bzshift,
    long sBias, long sC1, long sCz, long sWr, float scale)
{
    const int z    = blockIdx.z;
    const int col0 = blockIdx.x * 128;
    const int z1 = z >> bzshift;
    const int z2 = z - (z1 << bzshift);
    const float* Bb = Bp + (long)z1 * sBz + (long)z2 * sBz2;
    const float* biasb = biasp ? biasp + (long)z1 * sBias : nullptr;

    __shared__ __bf16 Ah[256 * 40];
    __shared__ __bf16 Al[ABF16 ? 64 : 256 * 40];
    __shared__ __bf16 Bh[128 * 40];
    __shared__ __bf16 Bl[BSING ? 64 : 128 * 40];

    const int tid  = threadIdx.x;
    const int lane = tid & 63;
    const int wid  = tid >> 6;
    const int wm = (wid >> 1) * 64;
    const int wn = (wid & 1) * 64;
    const int fr  = lane & 15;
    const int fkb = (lane >> 4) * 16;

    f32x4 acc[4][4] = {};
    bf16x8 pfah[2];
    float4 pfaf[2][2];
    float4 pfb[2];

    auto loadAB = [&](int k0) {
#pragma unroll
        for (int rep = 0; rep < 2; ++rep) {
            const int idx = tid + rep * 512;
            const int row = idx >> 2;
            const int cc4 = idx & 3;
            if (ABF16) {
                pfah[rep] = *(const bf16x8*)((const __bf16*)Ap + (long)z * sAz +
                                             (long)row * sA1 + k0 + cc4 * 8);
            } else {
                const float* src = (const float*)Ap + (long)z * sAz +
                                   (long)row * sA1 + k0 + cc4 * 8;
                pfaf[rep][0] = *(const float4*)src;
                pfaf[rep][1] = *(const float4*)(src + 4);
            }
        }
        {
            const int row = tid >> 2;
            const int cc4 = tid & 3;
            const float* src = Bb + (long)(col0 + row) * ldb + k0 + cc4 * 8;
            pfb[0] = *(const float4*)src;
            pfb[1] = *(const float4*)(src + 4);
        }
    };

    loadAB(0);
    for (int k0 = 0; k0 < K; k0 += 32) {
        __syncthreads();
#pragma unroll
        for (int rep = 0; rep < 2; ++rep) {
            const int idx = tid + rep * 512;
            const int row = idx >> 2;
            const int cc4 = idx & 3;
            if (ABF16) {
                *(bf16x8*)&Ah[row * 40 + cc4 * 8] = pfah[rep];
            } else {
                bf16x8 hi, lo;
                split8(pfaf[rep][0], pfaf[rep][1], hi, lo);
                *(bf16x8*)&Ah[row * 40 + cc4 * 8] = hi;
                *(bf16x8*)&Al[row * 40 + cc4 * 8] = lo;
            }
        }
        {
            const int row = tid >> 2;
            const int cc4 = tid & 3;
            bf16x8 hi, lo;
            split8(pfb[0], pfb[1], hi, lo);
            *(bf16x8*)&Bh[row * 40 + cc4 * 8] = hi;
            if (!BSING) *(bf16x8*)&Bl[row * 40 + cc4 * 8] = lo;
        }
        __syncthreads();
        if (k0 + 32 < K) loadAB(k0 + 32);

        bf16x8 bh4[4], bl4[4];
#pragma unroll
        for (int n = 0; n < 4; ++n) {
            bh4[n] = *(const bf16x8*)((const char*)&Bh[(wn + n * 16 + fr) * 40] + fkb);
            if (!BSING) bl4[n] = *(const bf16x8*)((const char*)&Bl[(wn + n * 16 + fr) * 40] + fkb);
        }
#pragma unroll
        for (int m = 0; m < 4; ++m) {
            const bf16x8 ah = *(const bf16x8*)((const char*)&Ah[(wm + m * 16 + fr) * 40] + fkb);
            bf16x8 al;
            if (!ABF16) al = *(const bf16x8*)((const char*)&Al[(wm + m * 16 + fr) * 40] + fkb);
#pragma unroll
            for (int n = 0; n < 4; ++n) {
                acc[m][n] = __builtin_amdgcn_mfma_f32_16x16x32_bf16(ah, bh4[n], acc[m][n], 0, 0, 0);
                if (!BSING) acc[m][n] = __builtin_amdgcn_mfma_f32_16x16x32_bf16(ah, bl4[n], acc[m][n], 0, 0, 0);
                if (!ABF16) acc[m][n] = __builtin_amdgcn_mfma_f32_16x16x32_bf16(al, bh4[n], acc[m][n], 0, 0, 0);
            }
        }
    }

    const int lr4 = (lane >> 4) * 4;
#pragma unroll
    for (int m = 0; m < 4; ++m) {
#pragma unroll
        for (int r = 0; r < 4; ++r) {
            const int rr = wm + m * 16 + lr4 + r;
#pragma unroll
            for (int n = 0; n < 4; ++n) {
                const int cc = col0 + wn + n * 16 + fr;
                float v = acc[m][n][r] * scale;
                if (biasp) v += biasb[cc];
                if (ACT == 1) v = 0.5f * v * (1.0f + erff(v * 0.70710678118654752f));
                if (WMUL) v *= wmulp[(long)rr * sWr + z];
                if (OUTH) Ch[(long)z * sCz + (long)rr * sC1 + cc] = (__bf16)v;
                else      Cf[(long)z * sCz + (long)rr * sC1 + cc] = v;
            }
        }
    }
}

// ===================== per-wave dot GEMM (tiny N) =====================
__global__ void dotk_k(const float* __restrict__ A, const float* __restrict__ Bw,
                       const float* __restrict__ bias, float* __restrict__ out,
                       int MN, int N, int K)
{
    const int idx = blockIdx.x * (blockDim.x >> 6) + (threadIdx.x >> 6);
    if (idx >= MN) return;
    const int m = idx / N, n = idx - m * N;
    const int lane = threadIdx.x & 63;
    const float* a = A + (long)m * K;
    const float* bb = Bw + (long)n * K;
    float s = 0.f;
    for (int k = lane * 4; k < K; k += 256) {
        const float4 av = *(const float4*)(a + k);
        const float4 bv = *(const float4*)(bb + k);
        s += av.x * bv.x + av.y * bv.y + av.z * bv.z + av.w * bv.w;
    }
    s = wave_sum(s);
    if (lane == 0) out[idx] = s + (bias ? bias[n] : 0.f);
}

// ===================== reduce-act =====================
template <int ACT>
__global__ void kred_k(const float* __restrict__ part, const float* __restrict__ bias,
                       float* __restrict__ out, int n, long stride, int nz, int biasMask)
{
    const int i = blockIdx.x * blockDim.x + threadIdx.x;
    if (i >= n) return;
    float v = 0.f;
    for (int z = 0; z < nz; ++z) v += part[(long)z * stride + i];
    if (bias) v += bias[i & biasMask];
    if (ACT == 2) v = 1.0f / (1.0f + expf(-v));
    out[i] = v;
}

// ===================== merged setup =====================
__global__ void cpy8_k(const float* s0, const float* s1, const float* s2, const float* s3,
                       const float* s4, const float* s5, const float* s6, const float* s7,
                       float* d0, float* d1, float* d2, float* d3,
                       float* d4, float* d5, float* d6, float* d7)
{
    const int seg = blockIdx.x >> 10;
    const int i = ((blockIdx.x & 1023) * 256 + threadIdx.x);
    const float* srcs[8] = {s0, s1, s2, s3, s4, s5, s6, s7};
    float* dsts[8] = {d0, d1, d2, d3, d4, d5, d6, d7};
    ((float4*)dsts[seg])[i] = ((const float4*)srcs[seg])[i];
}

__global__ void tT4_k(const float* s0, const float* s1, const float* s2, const float* s3,
                      float* d0, float* d1, float* d2, float* d3)
{
    __shared__ float t[32][33];
    const int seg = blockIdx.y >> 5;
    const float* src = seg == 0 ? s0 : seg == 1 ? s1 : seg == 2 ? s2 : s3;
    float* dst = seg == 0 ? d0 : seg == 1 ? d1 : seg == 2 ? d2 : d3;
    const int c0 = blockIdx.x * 32, r0 = (blockIdx.y & 31) * 32;
    const int tx = threadIdx.x & 31, ty = threadIdx.x >> 5;
#pragma unroll
    for (int i = 0; i < 4; ++i) {
        const int r = ty + i * 8;
        t[r][tx] = src[(long)(r0 + r) * 1024 + c0 + tx];
    }
    __syncthreads();
#pragma unroll
    for (int i = 0; i < 4; ++i) {
        const int r = ty + i * 8;
        dst[(long)(c0 + r) * 1024 + r0 + tx] = t[tx][r];
    }
}

__global__ void biascat_k(const float* __restrict__ ts_b, const float* __restrict__ ca_b,
                          const float* __restrict__ st_b,
                          const float* __restrict__ ts_ob, const float* __restrict__ ca_ob,
                          const float* __restrict__ st_ob,
                          float* __restrict__ BCAT, float* __restrict__ BKCAT,
                          float* __restrict__ WVB, float* __restrict__ WOB)
{
    const int i = blockIdx.x * blockDim.x + threadIdx.x;
    if (i >= 1024) return;
    BCAT[i] = ts_b[i]; BCAT[1024 + i] = ca_b[i];
    BCAT[2048 + i] = st_b[1024 + i]; BCAT[3072 + i] = st_b[2048 + i];
    BKCAT[i] = ts_b[1024 + i]; BKCAT[1024 + i] = ca_b[1024 + i]; BKCAT[2048 + i] = st_b[i];
    WVB[i] = ts_b[2048 + i]; WVB[1024 + i] = ca_b[2048 + i];
    WOB[i] = ts_ob[i]; WOB[1024 + i] = ca_ob[i]; WOB[2048 + i] = st_ob[i];
}

// ===================== glue kernels =====================
__global__ void headdot3_k(const float* __restrict__ QALL, const float* __restrict__ BKCAT,
                           float* __restrict__ out)
{
    const int idx = blockIdx.x * blockDim.x + threadIdx.x;
    if (idx >= 3 * B_ * T_ * NH_) return;
    const int mod = idx >> 15;
    const int b = (idx >> 7) & 255;
    const int t = (idx >> 3) & 15;
    const int h = idx & 7;
    const float* q = QALL + (long)(b * 16 + t) * 4096 + mod * 1024 + h * 128;
    const float* bb = BKCAT + mod * 1024 + h * 128;
    float sum = 0.f;
    for (int k = 0; k < DH_; ++k) sum += q[k] * bb[k];
    out[idx] = sum;
}

__global__ __launch_bounds__(64) void softpb_k(const float* __restrict__ sc3,
                                               float* __restrict__ pbar,
                                               float* __restrict__ attm)
{
    const int blk = blockIdx.x;
    const int h = blk & 7;
    const int b = (blk >> 3) & 255;
    const int mod = blk >> 11;
    const int lane = threadIdx.x;
    const float* base = sc3 + (long)mod * 8388608 + (long)b * 32768 + (long)h * 256;
    float v[16][4];
#pragma unroll
    for (int t = 0; t < 16; ++t) {
        const float* rowp = base + (long)t * 2048;
#pragma unroll
        for (int j = 0; j < 4; ++j) v[t][j] = rowp[j * 64 + lane];
    }
    if (mod < 2) {
        float pb[4] = {0.f, 0.f, 0.f, 0.f};
#pragma unroll
        for (int t = 0; t < 16; ++t) {
            float m = fmaxf(fmaxf(v[t][0], v[t][1]), fmaxf(v[t][2], v[t][3]));
            m = wave_max(m);
            const float e0 = expf(v[t][0] - m), e1 = expf(v[t][1] - m);
            const float e2 = expf(v[t][2] - m), e3 = expf(v[t][3] - m);
            const float inv = 1.f / wave_sum(e0 + e1 + e2 + e3);
            pb[0] += e0 * inv; pb[1] += e1 * inv; pb[2] += e2 * inv; pb[3] += e3 * inv;
        }
        float* pd = pbar + (long)mod * 524288 + (long)b * 2048 + h * 256;
#pragma unroll
        for (int j = 0; j < 4; ++j) pd[j * 64 + lane] = pb[j] * (1.0f / 16.f);
    } else {
        float am[16];
#pragma unroll
        for (int t = 0; t < 16; ++t) am[t] = 0.f;
#pragma unroll
        for (int j = 0; j < 4; ++j) {
            float mx = v[0][j];
#pragma unroll
            for (int t = 1; t < 16; ++t) mx = fmaxf(mx, v[t][j]);
            float e[16];
            float sum = 0.f;
#pragma unroll
            for (int t = 0; t < 16; ++t) { e[t] = expf(v[t][j] - mx); sum += e[t]; }
            const float inv = 1.f / sum;
#pragma unroll
            for (int t = 0; t < 16; ++t) am[t] += e[t] * inv;
        }
#pragma unroll
        for (int t = 0; t < 16; ++t) {
            const float sm = wave_sum(am[t]) * (1.0f / 256.f);
            if (lane == 0) attm[b * 128 + t * 8 + h] = sm;
        }
    }
}

__global__ __launch_bounds__(256) void ctxw2_k(const float* __restrict__ pbar,
                                               const float* __restrict__ hs,
                                               float* __restrict__ part)
{
    const int b = blockIdx.x;
    const int sc = blockIdx.y;
    __shared__ float pl[16][64];
    const int tid = threadIdx.x;
    for (int i = tid; i < 16 * 64; i += 256) {
        const int row = i >> 6;
        const int mod = row >> 3;
        pl[row][i & 63] = pbar[(long)mod * 524288 + (long)b * 2048 +
                               (row & 7) * 256 + sc * 64 + (i & 63)];
    }
    __syncthreads();
    const int k0 = tid * 4;
    float4 acc[16] = {};
    const float* hb = hs + (long)b * S_ * H_ + (long)sc * 64 * H_;
    for (int s = 0; s < 64; ++s) {
        const float4 vv = *(const float4*)(hb + (long)s * H_ + k0);
#pragma unroll
        for (int j = 0; j < 16; ++j) {
            const float p = pl[j][s];
            acc[j].x += p * vv.x; acc[j].y += p * vv.y;
            acc[j].z += p * vv.z; acc[j].w += p * vv.w;
        }
    }
    float* ob = part + (long)sc * 4194304;
#pragma unroll
    for (int j = 0; j < 16; ++j) {
        const int mod = j >> 3, hh = j & 7;
        *(float4*)(ob + (long)mod * 2097152 + (long)b * 8192 + hh * 1024 + k0) = acc[j];
    }
}

__global__ void ohead2_k(const float* __restrict__ attm, const float* __restrict__ QALL,
                         float* __restrict__ outb)
{
    const int idx = blockIdx.x * blockDim.x + threadIdx.x;
    if (idx >= B_ * H_) return;
    const int c = idx & (H_ - 1);
    const int b = idx >> 10;
    float sv = 0.f;
#pragma unroll
    for (int t = 0; t < T_; ++t)
        sv += attm[b * M128_ + t * NH_ + (c >> 7)] * QALL[(long)(b * 16 + t) * 4096 + 3072 + c];
    outb[idx] = sv;
}

__global__ void cat3_k(const float* __restrict__ vs, const float* __restrict__ vt,
                       const float* __restrict__ vo, float* __restrict__ out)
{
    const int idx = blockIdx.x * blockDim.x + threadIdx.x;
    if (idx >= B_ * 3 * H_) return;
    const int k = idx % (3 * H_);
    const int b = idx / (3 * H_);
    float v;
    if (k < H_)          v = vs[b * H_ + k];
    else if (k < 2 * H_) v = vt[b * H_ + k - H_];
    else                 v = vo[b * H_ + k - 2 * H_];
    out[idx] = v;
}

__global__ void ln_k(const float* __restrict__ cat3, const float* __restrict__ g,
                     const float* __restrict__ bta, float* __restrict__ out)
{
    const int b = blockIdx.x;
    const int tid = threadIdx.x;
    __shared__ float buf[3 * H_];
    __shared__ float red[4];
    const float* src = cat3 + (long)b * 3 * H_;
    float sv = 0.f;
    for (int i = tid; i < 3 * H_; i += 256) { const float x = src[i]; buf[i] = x; sv += x; }
    sv = wave_sum(sv);
    if ((tid & 63) == 0) red[tid >> 6] = sv;
    __syncthreads();
    const float mu = (red[0] + red[1] + red[2] + red[3]) * (1.f / (3 * H_));
    __syncthreads();
    float s2 = 0.f;
    for (int i = tid; i < 3 * H_; i += 256) { const float d0 = buf[i] - mu; s2 += d0 * d0; }
    s2 = wave_sum(s2);
    if ((tid & 63) == 0) red[tid >> 6] = s2;
    __syncthreads();
    const float var = (red[0] + red[1] + red[2] + red[3]) * (1.f / (3 * H_));
    const float rstd = rsqrtf(var + 1e-5f);
    float* dst = out + (long)b * 3 * H_;
    for (int i = tid; i < 3 * H_; i += 256)
        dst[i] = (buf[i] - mu) * rstd * g[i] + bta[i];
}

__global__ void mulf_k(const float* __restrict__ a, const float* __restrict__ b2,
                       float* __restrict__ out, int n)
{
    const int idx = blockIdx.x * blockDim.x + threadIdx.x;
    if (idx < n) out[idx] = a[idx] * b2[idx];
}

__global__ void fuse_k(const float* __restrict__ g, const float* __restrict__ flin,
                       const float* __restrict__ bil, float* __restrict__ fused,
                       __bf16* __restrict__ fusedh)
{
    const int idx = blockIdx.x * blockDim.x + threadIdx.x;
    if (idx >= B_ * H_) return;
    const float gg = g[idx];
    const float v = gg * flin[idx] + (1.f - gg) * bil[idx];
    fused[idx] = v;
    fusedh[idx] = (__bf16)v;
}

__global__ void catfv_k(const float* __restrict__ fused, const float* __restrict__ vt,
                        float* __restrict__ out)
{
    const int idx = blockIdx.x * blockDim.x + threadIdx.x;
    if (idx >= B_ * 2 * H_) return;
    const int k = idx % (2 * H_);
    const int b = idx / (2 * H_);
    out[idx] = (k < H_) ? fused[b * H_ + k] : vt[b * H_ + k - H_];
}

__global__ void route_k(const float* __restrict__ glog, float* __restrict__ gp)
{
    const int b = blockIdx.x * blockDim.x + threadIdx.x;
    if (b >= B_) return;
    const float x0 = glog[b * 3], x1 = glog[b * 3 + 1], x2 = glog[b * 3 + 2];
    const float m1 = fmaxf(x0, fmaxf(x1, x2));
    float thr;
    if (x0 == m1)      thr = fmaxf(x1, x2);
    else if (x1 == m1) thr = fmaxf(x0, x2);
    else               thr = fmaxf(x0, x1);
    const float y0 = (x0 >= thr) ? x0 : -1e9f;
    const float y1 = (x1 >= thr) ? x1 : -1e9f;
    const float y2 = (x2 >= thr) ? x2 : -1e9f;
    const float mm = fmaxf(y0, fmaxf(y1, y2));
    const float e0 = expf(y0 - mm), e1 = expf(y1 - mm), e2 = expf(y2 - mm);
    const float inv = 1.f / (e0 + e1 + e2);
    gp[b * 3] = e0 * inv; gp[b * 3 + 1] = e1 * inv; gp[b * 3 + 2] = e2 * inv;
}

__global__ void epsm_k(float* __restrict__ elog, const float* __restrict__ gp)
{
    const int idx = blockIdx.x * blockDim.x + threadIdx.x;
    if (idx >= B_ * G_) return;
    float* p = elog + (long)idx * E_;
    float m = p[0];
#pragma unroll
    for (int e = 1; e < E_; ++e) m = fmaxf(m, p[e]);
    float sum = 0.f;
    float v[E_];
#pragma unroll
    for (int e = 0; e < E_; ++e) { v[e] = expf(p[e] - m); sum += v[e]; }
    const float w = gp[idx] / sum;
#pragma unroll
    for (int e = 0; e < E_; ++e) p[e] = v[e] * w;
}

__global__ void moefinal_k(const float* __restrict__ part, const float* __restrict__ fused,
                           const float* __restrict__ wsc, const float* __restrict__ e_b2,
                           float* __restrict__ res)
{
    const int idx = blockIdx.x * blockDim.x + threadIdx.x;
    if (idx >= B_ * H_) return;
    const int b = idx >> 10;
    const int h = idx & (H_ - 1);
    float acc = fused[idx];
#pragma unroll 8
    for (int z = 0; z < 48; ++z) acc += part[(long)z * (B_ * H_) + idx];
    float ba = 0.f;
#pragma unroll
    for (int ge = 0; ge < GE_; ++ge) ba += wsc[b * GE_ + ge] * e_b2[ge * H_ + h];
    res[idx] = acc + ba;
}

// ===================== entry =====================
extern "C" void kernel_launch(void* const* d_in, const int* in_sizes, int n_in,
                              void* d_out, int out_size, void* d_ws, size_t ws_size,
                              hipStream_t stream)
{
    const float* h_sent  = (const float*)d_in[0];
    const float* h_term  = (const float*)d_in[1];
    const float* ts_in_w = (const float*)d_in[2];
    const float* ts_out_w= (const float*)d_in[3];
    const float* st_in_w = (const float*)d_in[4];
    const float* st_out_w= (const float*)d_in[5];
    const float* ca_in_w = (const float*)d_in[6];
    const float* ca_out_w= (const float*)d_in[7];
    const float* opq_w   = (const float*)d_in[8];
    const float* fuse_w  = (const float*)d_in[9];
    const float* gate_w  = (const float*)d_in[10];
    const float* bs_w    = (const float*)d_in[11];
    const float* bt_w    = (const float*)d_in[12];
    const float* bo_w    = (const float*)d_in[13];
    const float* cond_w  = (const float*)d_in[14];
    const float* gr_w    = (const float*)d_in[15];
    const float* er_w    = (const float*)d_in[16];
    const float* e_w1    = (const float*)d_in[17];
    const float* e_w2    = (const float*)d_in[18];
    const float* cls_w   = (const float*)d_in[19];
    const float* ts_in_b = (const float*)d_in[20];
    const float* ts_out_b= (const float*)d_in[21];
    const float* st_in_b = (const float*)d_in[22];
    const float* st_out_b= (const float*)d_in[23];
    const float* ca_in_b = (const float*)d_in[24];
    const float* ca_out_b= (const float*)d_in[25];
    const float* fuse_b  = (const float*)d_in[26];
    const float* gate_b  = (const float*)d_in[27];
    const float* bs_b    = (const float*)d_in[28];
    const float* bt_b    = (const float*)d_in[29];
    const float* bo_b    = (const float*)d_in[30];
    const float* cond_b  = (const float*)d_in[31];
    const float* gr_b    = (const float*)d_in[32];
    const float* er_b    = (const float*)d_in[33];
    const float* e_b1    = (const float*)d_in[34];
    const float* e_b2    = (const float*)d_in[35];
    const float* cls_b   = (const float*)d_in[36];
    const float* ln_b    = (const float*)d_in[37];
    const float* ln_g    = (const float*)d_in[38];
    (void)in_sizes; (void)n_in; (void)out_size; (void)ws_size;

    float* ws = (float*)d_ws;
    size_t off = 0;
    auto allocF = [&](size_t n) { float* p = ws + off; off += (n + 63) & ~(size_t)63; return p; };

    float* QALL  = allocF(16777216);
    float* WCAT  = allocF(4194304);
    float* BCAT  = allocF(4096);
    float* BKCAT = allocF(3072);
    float* wT3   = allocF(3145728);
    float* opqT  = allocF(1048576);
    float* WVCAT = allocF(2097152);
    float* WVB   = allocF(2048);
    float* WOCAT = allocF(3145728);
    float* WOB   = allocF(3072);
    float* OFFS3 = allocF(98304);
    float* SC3   = allocF(25165824);
    float* PBAR3 = allocF(1048576);
    float* CTXB3 = allocF(4194304);
    float* PARTC = allocF(16777216);
    float* OBAR3 = allocF(786432);
    float* VOUT3 = allocF(786432);
    float* ATTM  = allocF(32768);
    float* CAT3  = allocF(786432);
    float* LNC   = allocF(786432);
    float* FLIN  = allocF(262144);
    float* GATE  = allocF(262144);
    float* BSV   = allocF(65536);
    float* BTV   = allocF(65536);
    float* PROD  = allocF(65536);
    float* BIL   = allocF(262144);
    float* FUSED = allocF(262144);
    float* FUSEDH= allocF(131072);
    float* CATFV = allocF(524288);
    float* COND  = allocF(262144);
    float* GLOG  = allocF(1024);
    float* GP    = allocF(1024);
    float* ELOG  = allocF(8192);
    float* RES   = allocF(262144);
    float* PARTF = allocF(1048576);
    float* H1Wf  = allocF(12582912);
    float* PART  = allocF(12582912);
    __bf16* FUSEDbf = (__bf16*)FUSEDH;
    __bf16* H1W     = (__bf16*)H1Wf;
    float* VTERM = VOUT3;
    float* VOP   = VOUT3 + 262144;
    float* VSENT = VOUT3 + 524288;

    hipStream_t s = stream;
    const float rscale = 0.08838834764831845f;

    // ---------- precompute (merged) ----------
    cpy8_k<<<dim3(8 * 1024), dim3(256), 0, s>>>(
        ts_in_w, st_in_w + 1048576, st_in_w + 2097152, ts_in_w + 2097152,
        ca_in_w + 2097152, ts_out_w, ca_out_w, st_out_w,
        WCAT, WCAT + 2097152, WCAT + 3145728, WVCAT,
        WVCAT + 1048576, WOCAT, WOCAT + 1048576, WOCAT + 2097152);
    biascat_k<<<dim3(4), dim3(256), 0, s>>>(ts_in_b, ca_in_b, st_in_b,
                                            ts_out_b, ca_out_b, st_out_b,
                                            BCAT, BKCAT, WVB, WOB);
    tT4_k<<<dim3(32, 128), dim3(256), 0, s>>>(
        ts_in_w + 1048576, ca_in_w + 1048576, st_in_w, opq_w,
        wT3, wT3 + 1048576, wT3 + 2097152, opqT);

    // Wcomb_ca = Wq_ca @ opq_w
    sg2(s, 0, ca_in_w, opqT, nullptr, nullptr, WCAT + 1048576,
        8, 8, 1, 1024, 12, 0, 0, 1024, 0, 0, 1024, 0, 0, 0, 0,
        0, 1024, 0, 0, 0, 0, 1.f);

    // QALL
    sg2(s, 0, h_term, WCAT, BCAT, nullptr, QALL,
        32, 32, 1, 1024, 12, 0, 0, 1024, 0, 0, 1024, 0, 0, 0, 0,
        0, 4096, 0, 0, 0, 0, 1.f);

    headdot3_k<<<dim3(384), dim3(256), 0, s>>>(QALL, BKCAT, OFFS3);

    // FUSED A-fold + scores
    fsc_k<<<dim3(1, 1, 1024), dim3(512), 0, s>>>(QALL, wT3, h_sent, OFFS3, SC3, rscale);

    // fused softmax + pool
    softpb_k<<<dim3(3 * B_ * NH_), dim3(64), 0, s>>>(SC3, PBAR3, ATTM);

    // ctx weighted sum (s-split x4) + reduce
    ctxw2_k<<<dim3(B_, 4), dim3(256), 0, s>>>(PBAR3, h_sent, PARTC);
    kred_k<0><<<dim3(4194304 / 256), dim3(256), 0, s>>>(PARTC, nullptr, CTXB3,
                                                        4194304, 4194304, 4, 0);
    // ctx V-proj z=16
    sg2(s, 0, CTXB3, WVCAT, WVB, nullptr, OBAR3,
        1, 2, 16, 1024, 12, 3,
        0, 8192, 2097152, 1024,
        1024, 1048576, 131072, 1024, 128,
        0, 1024, 262144, 128, 0, 0, 1.f);

    // st path
    ohead2_k<<<dim3((B_ * H_ + 255) / 256), dim3(256), 0, s>>>(ATTM, QALL, OBAR3 + 524288);

    // out-proj z=3
    sg2(s, 0, OBAR3, WOCAT, WOB, nullptr, VOUT3,
        8, 2, 3, 1024, 12, 0,
        0, 1024, 262144, 0,
        1024, 1048576, 0, 1024, 0,
        0, 1024, 262144, 0, 0, 0, 1.f);

    // ---------- fusion head ----------
    cat3_k<<<dim3((B_ * 3 * H_ + 255) / 256), dim3(256), 0, s>>>(VSENT, VTERM, VOP, CAT3);
    ln_k<<<dim3(B_), dim3(256), 0, s>>>(CAT3, ln_g, ln_b, LNC);
    sg2(s, 0, LNC, fuse_w, nullptr, nullptr, PARTF,
        8, 2, 4, 768, 12, 2, 0, 3072, 0, 768, 3072, 0, 768, 0, 0,
        0, 1024, 0, 262144, 0, 0, 1.f);
    kred_k<0><<<dim3(1024), dim3(256), 0, s>>>(PARTF, fuse_b, FLIN, 262144, 262144, 4, 1023);
    sg2(s, 0, CAT3, gate_w, nullptr, nullptr, PARTF,
        8, 2, 4, 768, 12, 2, 0, 3072, 0, 768, 3072, 0, 768, 0, 0,
        0, 1024, 0, 262144, 0, 0, 1.f);
    kred_k<2><<<dim3(1024), dim3(256), 0, s>>>(PARTF, gate_b, GATE, 262144, 262144, 4, 1023);
    sg2(s, 0, VSENT, bs_w, nullptr, nullptr, PARTF,
        2, 2, 4, 256, 12, 2, 0, 1024, 0, 256, 1024, 0, 256, 0, 0,
        0, 256, 0, 65536, 0, 0, 1.f);
    kred_k<0><<<dim3(256), dim3(256), 0, s>>>(PARTF, bs_b, BSV, 65536, 65536, 4, 255);
    sg2(s, 0, VTERM, bt_w, nullptr, nullptr, PARTF,
        2, 2, 4, 256, 12, 2, 0, 1024, 0, 256, 1024, 0, 256, 0, 0,
        0, 256, 0, 65536, 0, 0, 1.f);
    kred_k<0><<<dim3(256), dim3(256), 0, s>>>(PARTF, bt_b, BTV, 65536, 65536, 4, 255);
    mulf_k<<<dim3((B_ * R_ + 255) / 256), dim3(256), 0, s>>>(BSV, BTV, PROD, B_ * R_);
    sg2(s, 0, PROD, bo_w, nullptr, nullptr, PARTF,
        8, 2, 2, 128, 12, 1, 0, 256, 0, 128, 256, 0, 128, 0, 0,
        0, 1024, 0, 262144, 0, 0, 1.f);
    kred_k<0><<<dim3(1024), dim3(256), 0, s>>>(PARTF, bo_b, BIL, 262144, 262144, 2, 1023);
    fuse_k<<<dim3((B_ * H_ + 255) / 256), dim3(256), 0, s>>>(GATE, FLIN, BIL, FUSED, FUSEDbf);
    catfv_k<<<dim3((B_ * 2 * H_ + 255) / 256), dim3(256), 0, s>>>(FUSED, VTERM, CATFV);
    sg2(s, 0, CATFV, cond_w, nullptr, nullptr, PARTF,
        8, 2, 4, 512, 12, 2, 0, 2048, 0, 512, 2048, 0, 512, 0, 0,
        0, 1024, 0, 262144, 0, 0, 1.f);
    kred_k<0><<<dim3(1024), dim3(256), 0, s>>>(PARTF, cond_b, COND, 262144, 262144, 4, 1023);

    // ---------- routing (per-wave dot kernels) ----------
    dotk_k<<<dim3(192), dim3(256), 0, s>>>(FUSED, gr_w, gr_b, GLOG, B_ * G_, G_, H_);
    route_k<<<dim3(1), dim3(256), 0, s>>>(GLOG, GP);
    dotk_k<<<dim3(1536), dim3(256), 0, s>>>(COND, er_w, er_b, ELOG, B_ * GE_, GE_, H_);
    epsm_k<<<dim3(3), dim3(256), 0, s>>>(ELOG, GP);

    // ---------- MoE ----------
    sgemm256_k<1, 1, 1, 1, 1><<<dim3(I_ / 128, 1, GE_), dim3(512), 0, s>>>(
        FUSEDbf, e_w1, e_b1, ELOG, nullptr, H1W,
        1024, H_, 0, H_, (long)I_ * H_, 0, 0, I_,
        (long)GE_ * I_, I_, GE_, 1.f);
    sgemm256_k<1, 1, 0, 0, 0><<<dim3(H_ / 128, 1, 2 * GE_), dim3(512), 0, s>>>(
        H1W, e_w2, nullptr, nullptr, PART, nullptr,
        2048, (long)GE_ * I_, 2048, I_, (long)H_ * I_, 2048, 1, 0,
        H_, (long)B_ * H_, 0, 1.f);
    moefinal_k<<<dim3(B_ * H_ / 256), dim3(256), 0, s>>>(PART, FUSED, ELOG, e_b2, RES);

    // ---------- classifier ----------
    dotk_k<<<dim3(192), dim3(256), 0, s>>>(RES, cls_w, cls_b, (float*)d_out, B_ * L_, L_, H_);
}

// Round 11
// 1763.995 us; speedup vs baseline: 1.4274x; 1.4274x over previous
//
#include <hip/hip_runtime.h>
#include <math.h>

// ---------------------------------------------------------------------------
// HAGMoE — round 11: R10 with the rule-#20 fix.
// R10's fsc_k spilled acc[2][4][2] to scratch (VGPR=52, 3.1 GB scratch writes)
// because `#pragma unroll 1` made `half`/`kc` runtime indices. Fully unroll
// so every acc index is compile-time. No other change.
// ---------------------------------------------------------------------------

#define B_    256
#define S_    256
#define T_    16
#define H_    1024
#define NH_   8
#define DH_   128
#define M128_ 128
#define G_    3
#define E_    8
#define I_    4096
#define R_    256
#define L_    3
#define GE_   24

using bf16x8 = __attribute__((ext_vector_type(8))) __bf16;
using f32x4  = __attribute__((ext_vector_type(4))) float;

__device__ inline float wave_sum(float v) {
    for (int o = 32; o > 0; o >>= 1) v += __shfl_xor(v, o);
    return v;
}
__device__ inline float wave_max(float v) {
    for (int o = 32; o > 0; o >>= 1) v = fmaxf(v, __shfl_xor(v, o));
    return v;
}

__device__ inline void split8(const float4& f0, const float4& f1, bf16x8& hi, bf16x8& lo)
{
    const float fv[8] = {f0.x, f0.y, f0.z, f0.w, f1.x, f1.y, f1.z, f1.w};
#pragma unroll
    for (int j = 0; j < 8; ++j) {
        const __bf16 h = (__bf16)fv[j];
        hi[j] = h; lo[j] = (__bf16)(fv[j] - (float)h);
    }
}

// ===================== FUSED A-fold + scores =====================
// grid (1,1,1024); zz = ((z&7)<<7)|(z>>3); b = zz>>2, mod = zz&3 (mod==3 exits).
__global__ __launch_bounds__(512) void fsc_k(
    const float* __restrict__ QALL, const float* __restrict__ wT3,
    const float* __restrict__ hs, const float* __restrict__ OFFS3,
    float* __restrict__ SC3, float rscale)
{
    const int zz = ((blockIdx.z & 7) << 7) | (blockIdx.z >> 3);
    const int b = zz >> 2, mod = zz & 3;
    if (mod == 3) return;

    __shared__ __bf16 A64h[128 * 72];
    __shared__ __bf16 A64l[128 * 72];
    __shared__ __bf16 Bh[128 * 40];
    __shared__ __bf16 Bl[128 * 40];

    const int tid  = threadIdx.x;
    const int lane = tid & 63;
    const int wid  = tid >> 6;          // 0..7 = head in phase1
    const int fr   = lane & 15;
    const int fk   = lane >> 4;         // 0..3
    const int wm2  = (wid >> 2) * 64;   // phase2 row block
    const int wn2  = (wid & 3) * 32;    // phase2 col block (within 128-half)

    // ---- hoist Q fragments (phase1 A-operand): row t=fr, head wid ----
    bf16x8 qh[4], ql[4];
    {
        const float* qb = QALL + ((long)(b * 16 + fr)) * 4096 + mod * 1024 + wid * 128;
#pragma unroll
        for (int jc = 0; jc < 4; ++jc) {
            const float* p = qb + jc * 32 + fk * 8;
            split8(*(const float4*)p, *(const float4*)(p + 4), qh[jc], ql[jc]);
        }
    }

    f32x4 acc[2][4][2] = {};
    const float* wbase = wT3 + (long)mod * 1048576 + wid * 128;
    const float* hb = hs + (long)b * 262144;

    for (int ks = 0; ks < 16; ++ks) {
        __syncthreads();   // previous phase2 done reading A64
        // ---- phase1: A64[:, ks*64 .. +64) ----
#pragma unroll
        for (int nt = 0; nt < 4; ++nt) {
            f32x4 pa = {};
            const float* wr = wbase + (long)(ks * 64 + nt * 16 + fr) * 1024;
#pragma unroll
            for (int jc = 0; jc < 4; ++jc) {
                const float* p = wr + jc * 32 + fk * 8;
                bf16x8 wh, wl;
                split8(*(const float4*)p, *(const float4*)(p + 4), wh, wl);
                pa = __builtin_amdgcn_mfma_f32_16x16x32_bf16(qh[jc], wh, pa, 0, 0, 0);
                pa = __builtin_amdgcn_mfma_f32_16x16x32_bf16(qh[jc], wl, pa, 0, 0, 0);
                pa = __builtin_amdgcn_mfma_f32_16x16x32_bf16(ql[jc], wh, pa, 0, 0, 0);
            }
            const int kl = nt * 16 + fr;   // C/D col = lane&15
#pragma unroll
            for (int r = 0; r < 4; ++r) {  // C/D row = (lane>>4)*4 + r = t
                const int m = (fk * 4 + r) * 8 + wid;
                const float v = pa[r];
                const __bf16 hv = (__bf16)v;
                A64h[m * 72 + kl] = hv;
                A64l[m * 72 + kl] = (__bf16)(v - (float)hv);
            }
        }
        // ---- phase2: acc += A64 @ h_sent_chunk (FULLY UNROLLED: rule #20) ----
#pragma unroll
        for (int half = 0; half < 2; ++half) {
#pragma unroll
            for (int kc = 0; kc < 2; ++kc) {
                __syncthreads();   // Bh free (also: A64 ready on first pass)
                {
                    const int r2 = tid >> 2, q2 = tid & 3;
                    const float* p = hb + (long)(half * 128 + r2) * 1024 +
                                     ks * 64 + kc * 32 + q2 * 8;
                    bf16x8 hh, hl;
                    split8(*(const float4*)p, *(const float4*)(p + 4), hh, hl);
                    *(bf16x8*)&Bh[r2 * 40 + q2 * 8] = hh;
                    *(bf16x8*)&Bl[r2 * 40 + q2 * 8] = hl;
                }
                __syncthreads();
                const int klo = kc * 32 + fk * 8;
#pragma unroll
                for (int mt = 0; mt < 4; ++mt) {
                    const bf16x8 ah = *(const bf16x8*)&A64h[(wm2 + mt * 16 + fr) * 72 + klo];
                    const bf16x8 al = *(const bf16x8*)&A64l[(wm2 + mt * 16 + fr) * 72 + klo];
#pragma unroll
                    for (int nt = 0; nt < 2; ++nt) {
                        const bf16x8 bh = *(const bf16x8*)&Bh[(wn2 + nt * 16 + fr) * 40 + fk * 8];
                        const bf16x8 bl = *(const bf16x8*)&Bl[(wn2 + nt * 16 + fr) * 40 + fk * 8];
                        acc[half][mt][nt] = __builtin_amdgcn_mfma_f32_16x16x32_bf16(ah, bh, acc[half][mt][nt], 0, 0, 0);
                        acc[half][mt][nt] = __builtin_amdgcn_mfma_f32_16x16x32_bf16(ah, bl, acc[half][mt][nt], 0, 0, 0);
                        acc[half][mt][nt] = __builtin_amdgcn_mfma_f32_16x16x32_bf16(al, bh, acc[half][mt][nt], 0, 0, 0);
                    }
                }
            }
        }
    }

    // ---- epilogue ----
    float* out = SC3 + (long)mod * 8388608 + (long)b * 32768;
    const float* ro = OFFS3 + mod * 32768 + b * 128;
    const int lr4 = fk * 4;
#pragma unroll
    for (int half = 0; half < 2; ++half)
#pragma unroll
        for (int mt = 0; mt < 4; ++mt)
#pragma unroll
            for (int r = 0; r < 4; ++r) {
                const int rr = wm2 + mt * 16 + lr4 + r;
                const float rov = ro[rr];
#pragma unroll
                for (int nt = 0; nt < 2; ++nt) {
                    const int cc = half * 128 + wn2 + nt * 16 + fr;
                    out[(long)rr * 256 + cc] = (acc[half][mt][nt][r] + rov) * rscale;
                }
            }
}

// ===================== split-bf16 MFMA GEMM, 128x128, prefetched =============
template <int ACT>
__global__ __launch_bounds__(256) void sgemm2_k(
    const float* __restrict__ Ap, const float* __restrict__ Bp,
    const float* __restrict__ biasp, const float* __restrict__ roffp,
    float* __restrict__ Cf,
    int K, int m2shift, int zshift,
    long sA1, long sA2, long sAz1, long sAz2,
    long ldb, long sBz1, long sBz2, long sBia1, long sBia2,
    long sC1, long sC2, long sCz1, long sCz2, long sR1, long sR2,
    float scale)
{
    const int z  = blockIdx.z;
    const int z1 = z >> zshift;
    const int z2 = z & ((1 << zshift) - 1);
    const int m2mask = (1 << m2shift) - 1;
    const int row0 = blockIdx.y * 128;
    const int col0 = blockIdx.x * 128;
    const float* Ab = Ap + (long)z1 * sAz1 + (long)z2 * sAz2;
    const float* Bb = Bp + (long)z1 * sBz1 + (long)z2 * sBz2;
    const float* biasb = biasp ? biasp + (long)z1 * sBia1 + (long)z2 * sBia2 : nullptr;
    const float* roffb = roffp ? roffp + (long)z1 * sR1 + (long)z2 * sR2 : nullptr;

    __shared__ __bf16 Ahs[128 * 40];
    __shared__ __bf16 Als[128 * 40];
    __shared__ __bf16 Bhs[128 * 40];
    __shared__ __bf16 Bls[128 * 40];

    const int tid  = threadIdx.x;
    const int lane = tid & 63;
    const int wid  = tid >> 6;
    const int wm = (wid >> 1) * 64;
    const int wn = (wid & 1) * 64;
    const int fr  = lane & 15;
    const int fkb = (lane >> 4) * 16;
    const int qrow = tid >> 2;
    const int c4   = tid & 3;

    f32x4 acc[4][4] = {};
    float4 pfa[2][2], pfb[2][2];

    auto loadAB = [&](int k0) {
#pragma unroll
        for (int rep = 0; rep < 2; ++rep) {
            const int row = qrow + rep * 64;
            const int r = row0 + row;
            const int r1 = r >> m2shift, r2 = r & m2mask;
            const float* srcA = Ab + (long)r1 * sA1 + (long)r2 * sA2 + k0 + c4 * 8;
            pfa[rep][0] = *(const float4*)srcA;
            pfa[rep][1] = *(const float4*)(srcA + 4);
            const float* srcB = Bb + (long)(col0 + row) * ldb + k0 + c4 * 8;
            pfb[rep][0] = *(const float4*)srcB;
            pfb[rep][1] = *(const float4*)(srcB + 4);
        }
    };

    loadAB(0);
    for (int k0 = 0; k0 < K; k0 += 32) {
        __syncthreads();
#pragma unroll
        for (int rep = 0; rep < 2; ++rep) {
            const int row = qrow + rep * 64;
            bf16x8 hi, lo;
            split8(pfa[rep][0], pfa[rep][1], hi, lo);
            *(bf16x8*)&Ahs[row * 40 + c4 * 8] = hi;
            *(bf16x8*)&Als[row * 40 + c4 * 8] = lo;
            split8(pfb[rep][0], pfb[rep][1], hi, lo);
            *(bf16x8*)&Bhs[row * 40 + c4 * 8] = hi;
            *(bf16x8*)&Bls[row * 40 + c4 * 8] = lo;
        }
        __syncthreads();
        if (k0 + 32 < K) loadAB(k0 + 32);

        bf16x8 bh4[4], bl4[4];
#pragma unroll
        for (int n = 0; n < 4; ++n) {
            bh4[n] = *(const bf16x8*)((const char*)&Bhs[(wn + n * 16 + fr) * 40] + fkb);
            bl4[n] = *(const bf16x8*)((const char*)&Bls[(wn + n * 16 + fr) * 40] + fkb);
        }
#pragma unroll
        for (int m = 0; m < 4; ++m) {
            const bf16x8 ah = *(const bf16x8*)((const char*)&Ahs[(wm + m * 16 + fr) * 40] + fkb);
            const bf16x8 al = *(const bf16x8*)((const char*)&Als[(wm + m * 16 + fr) * 40] + fkb);
#pragma unroll
            for (int n = 0; n < 4; ++n) {
                acc[m][n] = __builtin_amdgcn_mfma_f32_16x16x32_bf16(ah, bh4[n], acc[m][n], 0, 0, 0);
                acc[m][n] = __builtin_amdgcn_mfma_f32_16x16x32_bf16(ah, bl4[n], acc[m][n], 0, 0, 0);
                acc[m][n] = __builtin_amdgcn_mfma_f32_16x16x32_bf16(al, bh4[n], acc[m][n], 0, 0, 0);
            }
        }
    }

    float* Cfb = Cf + (long)z1 * sCz1 + (long)z2 * sCz2;
    const int lr4 = (lane >> 4) * 4;
#pragma unroll
    for (int m = 0; m < 4; ++m) {
#pragma unroll
        for (int r = 0; r < 4; ++r) {
            const int rr = row0 + wm + m * 16 + lr4 + r;
            const int r1 = rr >> m2shift, r2 = rr & m2mask;
            const float ro = roffb ? roffb[rr] : 0.f;
            const long cb = (long)r1 * sC1 + (long)r2 * sC2;
#pragma unroll
            for (int n = 0; n < 4; ++n) {
                const int cc = col0 + wn + n * 16 + fr;
                float v = (acc[m][n][r] + ro) * scale;
                if (biasp) v += biasb[cc];
                if (ACT == 2) v = 1.0f / (1.0f + expf(-v));
                Cfb[cb + cc] = v;
            }
        }
    }
}

static void sg2(hipStream_t s, int act,
                const float* A, const float* B, const float* bias, const float* roff,
                float* C, int gx, int gy, int gz,
                int K, int m2shift, int zshift,
                long sA1, long sA2, long sAz1, long sAz2,
                long ldb, long sBz1, long sBz2, long sBia1, long sBia2,
                long sC1, long sC2, long sCz1, long sCz2, long sR1, long sR2,
                float scale)
{
    dim3 g(gx, gy, gz), b(256);
#define S2ARGS A, B, bias, roff, C, K, m2shift, zshift, sA1, sA2, sAz1, sAz2, \
               ldb, sBz1, sBz2, sBia1, sBia2, sC1, sC2, sCz1, sCz2, sR1, sR2, scale
    if (act == 2) sgemm2_k<2><<<g, b, 0, s>>>(S2ARGS);
    else          sgemm2_k<0><<<g, b, 0, s>>>(S2ARGS);
#undef S2ARGS
}

// ===================== 256x128 MFMA GEMM (MoE), prefetched =====================
template <int ABF16, int BSING, int ACT, int WMUL, int OUTH>
__global__ __launch_bounds__(512) void sgemm256_k(
    const void* __restrict__ Ap, const float* __restrict__ Bp,
    const float* __restrict__ biasp, const float* __restrict__ wmulp,
    float* __restrict__ Cf, __bf16* __restrict__ Ch,
    int K, long sA1, long sAz, long ldb, long sBz, long sBz2, int bzshift,
    long sBias, long sC1, long sCz, long sWr, float scale)
{
    const int z    = blockIdx.z;
    const int col0 = blockIdx.x * 128;
    const int z1 = z >> bzshift;
    const int z2 = z - (z1 << bzshift);
    const float* Bb = Bp + (long)z1 * sBz + (long)z2 * sBz2;
    const float* biasb = biasp ? biasp + (long)z1 * sBias : nullptr;

    __shared__ __bf16 Ah[256 * 40];
    __shared__ __bf16 Al[ABF16 ? 64 : 256 * 40];
    __shared__ __bf16 Bh[128 * 40];
    __shared__ __bf16 Bl[BSING ? 64 : 128 * 40];

    const int tid  = threadIdx.x;
    const int lane = tid & 63;
    const int wid  = tid >> 6;
    const int wm = (wid >> 1) * 64;
    const int wn = (wid & 1) * 64;
    const int fr  = lane & 15;
    const int fkb = (lane >> 4) * 16;

    f32x4 acc[4][4] = {};
    bf16x8 pfah[2];
    float4 pfaf[2][2];
    float4 pfb[2];

    auto loadAB = [&](int k0) {
#pragma unroll
        for (int rep = 0; rep < 2; ++rep) {
            const int idx = tid + rep * 512;
            const int row = idx >> 2;
            const int cc4 = idx & 3;
            if (ABF16) {
                pfah[rep] = *(const bf16x8*)((const __bf16*)Ap + (long)z * sAz +
                                             (long)row * sA1 + k0 + cc4 * 8);
            } else {
                const float* src = (const float*)Ap + (long)z * sAz +
                                   (long)row * sA1 + k0 + cc4 * 8;
                pfaf[rep][0] = *(const float4*)src;
                pfaf[rep][1] = *(const float4*)(src + 4);
            }
        }
        {
            const int row = tid >> 2;
            const int cc4 = tid & 3;
            const float* src = Bb + (long)(col0 + row) * ldb + k0 + cc4 * 8;
            pfb[0] = *(const float4*)src;
            pfb[1] = *(const float4*)(src + 4);
        }
    };

    loadAB(0);
    for (int k0 = 0; k0 < K; k0 += 32) {
        __syncthreads();
#pragma unroll
        for (int rep = 0; rep < 2; ++rep) {
            const int idx = tid + rep * 512;
            const int row = idx >> 2;
            const int cc4 = idx & 3;
            if (ABF16) {
                *(bf16x8*)&Ah[row * 40 + cc4 * 8] = pfah[rep];
            } else {
                bf16x8 hi, lo;
                split8(pfaf[rep][0], pfaf[rep][1], hi, lo);
                *(bf16x8*)&Ah[row * 40 + cc4 * 8] = hi;
                *(bf16x8*)&Al[row * 40 + cc4 * 8] = lo;
            }
        }
        {
            const int row = tid >> 2;
            const int cc4 = tid & 3;
            bf16x8 hi, lo;
            split8(pfb[0], pfb[1], hi, lo);
            *(bf16x8*)&Bh[row * 40 + cc4 * 8] = hi;
            if (!BSING) *(bf16x8*)&Bl[row * 40 + cc4 * 8] = lo;
        }
        __syncthreads();
        if (k0 + 32 < K) loadAB(k0 + 32);

        bf16x8 bh4[4], bl4[4];
#pragma unroll
        for (int n = 0; n < 4; ++n) {
            bh4[n] = *(const bf16x8*)((const char*)&Bh[(wn + n * 16 + fr) * 40] + fkb);
            if (!BSING) bl4[n] = *(const bf16x8*)((const char*)&Bl[(wn + n * 16 + fr) * 40] + fkb);
        }
#pragma unroll
        for (int m = 0; m < 4; ++m) {
            const bf16x8 ah = *(const bf16x8*)((const char*)&Ah[(wm + m * 16 + fr) * 40] + fkb);
            bf16x8 al;
            if (!ABF16) al = *(const bf16x8*)((const char*)&Al[(wm + m * 16 + fr) * 40] + fkb);
#pragma unroll
            for (int n = 0; n < 4; ++n) {
                acc[m][n] = __builtin_amdgcn_mfma_f32_16x16x32_bf16(ah, bh4[n], acc[m][n], 0, 0, 0);
                if (!BSING) acc[m][n] = __builtin_amdgcn_mfma_f32_16x16x32_bf16(ah, bl4[n], acc[m][n], 0, 0, 0);
                if (!ABF16) acc[m][n] = __builtin_amdgcn_mfma_f32_16x16x32_bf16(al, bh4[n], acc[m][n], 0, 0, 0);
            }
        }
    }

    const int lr4 = (lane >> 4) * 4;
#pragma unroll
    for (int m = 0; m < 4; ++m) {
#pragma unroll
        for (int r = 0; r < 4; ++r) {
            const int rr = wm + m * 16 + lr4 + r;
#pragma unroll
            for (int n = 0; n < 4; ++n) {
                const int cc = col0 + wn + n * 16 + fr;
                float v = acc[m][n][r] * scale;
                if (biasp) v += biasb[cc];
                if (ACT == 1) v = 0.5f * v * (1.0f + erff(v * 0.70710678118654752f));
                if (WMUL) v *= wmulp[(long)rr * sWr + z];
                if (OUTH) Ch[(long)z * sCz + (long)rr * sC1 + cc] = (__bf16)v;
                else      Cf[(long)z * sCz + (long)rr * sC1 + cc] = v;
            }
        }
    }
}

// ===================== per-wave dot GEMM (tiny N) =====================
__global__ void dotk_k(const float* __restrict__ A, const float* __restrict__ Bw,
                       const float* __restrict__ bias, float* __restrict__ out,
                       int MN, int N, int K)
{
    const int idx = blockIdx.x * (blockDim.x >> 6) + (threadIdx.x >> 6);
    if (idx >= MN) return;
    const int m = idx / N, n = idx - m * N;
    const int lane = threadIdx.x & 63;
    const float* a = A + (long)m * K;
    const float* bb = Bw + (long)n * K;
    float s = 0.f;
    for (int k = lane * 4; k < K; k += 256) {
        const float4 av = *(const float4*)(a + k);
        const float4 bv = *(const float4*)(bb + k);
        s += av.x * bv.x + av.y * bv.y + av.z * bv.z + av.w * bv.w;
    }
    s = wave_sum(s);
    if (lane == 0) out[idx] = s + (bias ? bias[n] : 0.f);
}

// ===================== reduce-act =====================
template <int ACT>
__global__ void kred_k(const float* __restrict__ part, const float* __restrict__ bias,
                       float* __restrict__ out, int n, long stride, int nz, int biasMask)
{
    const int i = blockIdx.x * blockDim.x + threadIdx.x;
    if (i >= n) return;
    float v = 0.f;
    for (int z = 0; z < nz; ++z) v += part[(long)z * stride + i];
    if (bias) v += bias[i & biasMask];
    if (ACT == 2) v = 1.0f / (1.0f + expf(-v));
    out[i] = v;
}

// ===================== merged setup =====================
__global__ void cpy8_k(const float* s0, const float* s1, const float* s2, const float* s3,
                       const float* s4, const float* s5, const float* s6, const float* s7,
                       float* d0, float* d1, float* d2, float* d3,
                       float* d4, float* d5, float* d6, float* d7)
{
    const int seg = blockIdx.x >> 10;
    const int i = ((blockIdx.x & 1023) * 256 + threadIdx.x);
    const float* srcs[8] = {s0, s1, s2, s3, s4, s5, s6, s7};
    float* dsts[8] = {d0, d1, d2, d3, d4, d5, d6, d7};
    ((float4*)dsts[seg])[i] = ((const float4*)srcs[seg])[i];
}

__global__ void tT4_k(const float* s0, const float* s1, const float* s2, const float* s3,
                      float* d0, float* d1, float* d2, float* d3)
{
    __shared__ float t[32][33];
    const int seg = blockIdx.y >> 5;
    const float* src = seg == 0 ? s0 : seg == 1 ? s1 : seg == 2 ? s2 : s3;
    float* dst = seg == 0 ? d0 : seg == 1 ? d1 : seg == 2 ? d2 : d3;
    const int c0 = blockIdx.x * 32, r0 = (blockIdx.y & 31) * 32;
    const int tx = threadIdx.x & 31, ty = threadIdx.x >> 5;
#pragma unroll
    for (int i = 0; i < 4; ++i) {
        const int r = ty + i * 8;
        t[r][tx] = src[(long)(r0 + r) * 1024 + c0 + tx];
    }
    __syncthreads();
#pragma unroll
    for (int i = 0; i < 4; ++i) {
        const int r = ty + i * 8;
        dst[(long)(c0 + r) * 1024 + r0 + tx] = t[tx][r];
    }
}

__global__ void biascat_k(const float* __restrict__ ts_b, const float* __restrict__ ca_b,
                          const float* __restrict__ st_b,
                          const float* __restrict__ ts_ob, const float* __restrict__ ca_ob,
                          const float* __restrict__ st_ob,
                          float* __restrict__ BCAT, float* __restrict__ BKCAT,
                          float* __restrict__ WVB, float* __restrict__ WOB)
{
    const int i = blockIdx.x * blockDim.x + threadIdx.x;
    if (i >= 1024) return;
    BCAT[i] = ts_b[i]; BCAT[1024 + i] = ca_b[i];
    BCAT[2048 + i] = st_b[1024 + i]; BCAT[3072 + i] = st_b[2048 + i];
    BKCAT[i] = ts_b[1024 + i]; BKCAT[1024 + i] = ca_b[1024 + i]; BKCAT[2048 + i] = st_b[i];
    WVB[i] = ts_b[2048 + i]; WVB[1024 + i] = ca_b[2048 + i];
    WOB[i] = ts_ob[i]; WOB[1024 + i] = ca_ob[i]; WOB[2048 + i] = st_ob[i];
}

// ===================== glue kernels =====================
__global__ void headdot3_k(const float* __restrict__ QALL, const float* __restrict__ BKCAT,
                           float* __restrict__ out)
{
    const int idx = blockIdx.x * blockDim.x + threadIdx.x;
    if (idx >= 3 * B_ * T_ * NH_) return;
    const int mod = idx >> 15;
    const int b = (idx >> 7) & 255;
    const int t = (idx >> 3) & 15;
    const int h = idx & 7;
    const float* q = QALL + (long)(b * 16 + t) * 4096 + mod * 1024 + h * 128;
    const float* bb = BKCAT + mod * 1024 + h * 128;
    float sum = 0.f;
    for (int k = 0; k < DH_; ++k) sum += q[k] * bb[k];
    out[idx] = sum;
}

__global__ __launch_bounds__(64) void softpb_k(const float* __restrict__ sc3,
                                               float* __restrict__ pbar,
                                               float* __restrict__ attm)
{
    const int blk = blockIdx.x;
    const int h = blk & 7;
    const int b = (blk >> 3) & 255;
    const int mod = blk >> 11;
    const int lane = threadIdx.x;
    const float* base = sc3 + (long)mod * 8388608 + (long)b * 32768 + (long)h * 256;
    float v[16][4];
#pragma unroll
    for (int t = 0; t < 16; ++t) {
        const float* rowp = base + (long)t * 2048;
#pragma unroll
        for (int j = 0; j < 4; ++j) v[t][j] = rowp[j * 64 + lane];
    }
    if (mod < 2) {
        float pb[4] = {0.f, 0.f, 0.f, 0.f};
#pragma unroll
        for (int t = 0; t < 16; ++t) {
            float m = fmaxf(fmaxf(v[t][0], v[t][1]), fmaxf(v[t][2], v[t][3]));
            m = wave_max(m);
            const float e0 = expf(v[t][0] - m), e1 = expf(v[t][1] - m);
            const float e2 = expf(v[t][2] - m), e3 = expf(v[t][3] - m);
            const float inv = 1.f / wave_sum(e0 + e1 + e2 + e3);
            pb[0] += e0 * inv; pb[1] += e1 * inv; pb[2] += e2 * inv; pb[3] += e3 * inv;
        }
        float* pd = pbar + (long)mod * 524288 + (long)b * 2048 + h * 256;
#pragma unroll
        for (int j = 0; j < 4; ++j) pd[j * 64 + lane] = pb[j] * (1.0f / 16.f);
    } else {
        float am[16];
#pragma unroll
        for (int t = 0; t < 16; ++t) am[t] = 0.f;
#pragma unroll
        for (int j = 0; j < 4; ++j) {
            float mx = v[0][j];
#pragma unroll
            for (int t = 1; t < 16; ++t) mx = fmaxf(mx, v[t][j]);
            float e[16];
            float sum = 0.f;
#pragma unroll
            for (int t = 0; t < 16; ++t) { e[t] = expf(v[t][j] - mx); sum += e[t]; }
            const float inv = 1.f / sum;
#pragma unroll
            for (int t = 0; t < 16; ++t) am[t] += e[t] * inv;
        }
#pragma unroll
        for (int t = 0; t < 16; ++t) {
            const float sm = wave_sum(am[t]) * (1.0f / 256.f);
            if (lane == 0) attm[b * 128 + t * 8 + h] = sm;
        }
    }
}

__global__ __launch_bounds__(256) void ctxw2_k(const float* __restrict__ pbar,
                                               const float* __restrict__ hs,
                                               float* __restrict__ part)
{
    const int b = blockIdx.x;
    const int sc = blockIdx.y;
    __shared__ float pl[16][64];
    const int tid = threadIdx.x;
    for (int i = tid; i < 16 * 64; i += 256) {
        const int row = i >> 6;
        const int mod = row >> 3;
        pl[row][i & 63] = pbar[(long)mod * 524288 + (long)b * 2048 +
                               (row & 7) * 256 + sc * 64 + (i & 63)];
    }
    __syncthreads();
    const int k0 = tid * 4;
    float4 acc[16] = {};
    const float* hb = hs + (long)b * S_ * H_ + (long)sc * 64 * H_;
    for (int s = 0; s < 64; ++s) {
        const float4 vv = *(const float4*)(hb + (long)s * H_ + k0);
#pragma unroll
        for (int j = 0; j < 16; ++j) {
            const float p = pl[j][s];
            acc[j].x += p * vv.x; acc[j].y += p * vv.y;
            acc[j].z += p * vv.z; acc[j].w += p * vv.w;
        }
    }
    float* ob = part + (long)sc * 4194304;
#pragma unroll
    for (int j = 0; j < 16; ++j) {
        const int mod = j >> 3, hh = j & 7;
        *(float4*)(ob + (long)mod * 2097152 + (long)b * 8192 + hh * 1024 + k0) = acc[j];
    }
}

__global__ void ohead2_k(const float* __restrict__ attm, const float* __restrict__ QALL,
                         float* __restrict__ outb)
{
    const int idx = blockIdx.x * blockDim.x + threadIdx.x;
    if (idx >= B_ * H_) return;
    const int c = idx & (H_ - 1);
    const int b = idx >> 10;
    float sv = 0.f;
#pragma unroll
    for (int t = 0; t < T_; ++t)
        sv += attm[b * M128_ + t * NH_ + (c >> 7)] * QALL[(long)(b * 16 + t) * 4096 + 3072 + c];
    outb[idx] = sv;
}

__global__ void cat3_k(const float* __restrict__ vs, const float* __restrict__ vt,
                       const float* __restrict__ vo, float* __restrict__ out)
{
    const int idx = blockIdx.x * blockDim.x + threadIdx.x;
    if (idx >= B_ * 3 * H_) return;
    const int k = idx % (3 * H_);
    const int b = idx / (3 * H_);
    float v;
    if (k < H_)          v = vs[b * H_ + k];
    else if (k < 2 * H_) v = vt[b * H_ + k - H_];
    else                 v = vo[b * H_ + k - 2 * H_];
    out[idx] = v;
}

__global__ void ln_k(const float* __restrict__ cat3, const float* __restrict__ g,
                     const float* __restrict__ bta, float* __restrict__ out)
{
    const int b = blockIdx.x;
    const int tid = threadIdx.x;
    __shared__ float buf[3 * H_];
    __shared__ float red[4];
    const float* src = cat3 + (long)b * 3 * H_;
    float sv = 0.f;
    for (int i = tid; i < 3 * H_; i += 256) { const float x = src[i]; buf[i] = x; sv += x; }
    sv = wave_sum(sv);
    if ((tid & 63) == 0) red[tid >> 6] = sv;
    __syncthreads();
    const float mu = (red[0] + red[1] + red[2] + red[3]) * (1.f / (3 * H_));
    __syncthreads();
    float s2 = 0.f;
    for (int i = tid; i < 3 * H_; i += 256) { const float d0 = buf[i] - mu; s2 += d0 * d0; }
    s2 = wave_sum(s2);
    if ((tid & 63) == 0) red[tid >> 6] = s2;
    __syncthreads();
    const float var = (red[0] + red[1] + red[2] + red[3]) * (1.f / (3 * H_));
    const float rstd = rsqrtf(var + 1e-5f);
    float* dst = out + (long)b * 3 * H_;
    for (int i = tid; i < 3 * H_; i += 256)
        dst[i] = (buf[i] - mu) * rstd * g[i] + bta[i];
}

__global__ void mulf_k(const float* __restrict__ a, const float* __restrict__ b2,
                       float* __restrict__ out, int n)
{
    const int idx = blockIdx.x * blockDim.x + threadIdx.x;
    if (idx < n) out[idx] = a[idx] * b2[idx];
}

__global__ void fuse_k(const float* __restrict__ g, const float* __restrict__ flin,
                       const float* __restrict__ bil, float* __restrict__ fused,
                       __bf16* __restrict__ fusedh)
{
    const int idx = blockIdx.x * blockDim.x + threadIdx.x;
    if (idx >= B_ * H_) return;
    const float gg = g[idx];
    const float v = gg * flin[idx] + (1.f - gg) * bil[idx];
    fused[idx] = v;
    fusedh[idx] = (__bf16)v;
}

__global__ void catfv_k(const float* __restrict__ fused, const float* __restrict__ vt,
                        float* __restrict__ out)
{
    const int idx = blockIdx.x * blockDim.x + threadIdx.x;
    if (idx >= B_ * 2 * H_) return;
    const int k = idx % (2 * H_);
    const int b = idx / (2 * H_);
    out[idx] = (k < H_) ? fused[b * H_ + k] : vt[b * H_ + k - H_];
}

__global__ void route_k(const float* __restrict__ glog, float* __restrict__ gp)
{
    const int b = blockIdx.x * blockDim.x + threadIdx.x;
    if (b >= B_) return;
    const float x0 = glog[b * 3], x1 = glog[b * 3 + 1], x2 = glog[b * 3 + 2];
    const float m1 = fmaxf(x0, fmaxf(x1, x2));
    float thr;
    if (x0 == m1)      thr = fmaxf(x1, x2);
    else if (x1 == m1) thr = fmaxf(x0, x2);
    else               thr = fmaxf(x0, x1);
    const float y0 = (x0 >= thr) ? x0 : -1e9f;
    const float y1 = (x1 >= thr) ? x1 : -1e9f;
    const float y2 = (x2 >= thr) ? x2 : -1e9f;
    const float mm = fmaxf(y0, fmaxf(y1, y2));
    const float e0 = expf(y0 - mm), e1 = expf(y1 - mm), e2 = expf(y2 - mm);
    const float inv = 1.f / (e0 + e1 + e2);
    gp[b * 3] = e0 * inv; gp[b * 3 + 1] = e1 * inv; gp[b * 3 + 2] = e2 * inv;
}

__global__ void epsm_k(float* __restrict__ elog, const float* __restrict__ gp)
{
    const int idx = blockIdx.x * blockDim.x + threadIdx.x;
    if (idx >= B_ * G_) return;
    float* p = elog + (long)idx * E_;
    float m = p[0];
#pragma unroll
    for (int e = 1; e < E_; ++e) m = fmaxf(m, p[e]);
    float sum = 0.f;
    float v[E_];
#pragma unroll
    for (int e = 0; e < E_; ++e) { v[e] = expf(p[e] - m); sum += v[e]; }
    const float w = gp[idx] / sum;
#pragma unroll
    for (int e = 0; e < E_; ++e) p[e] = v[e] * w;
}

__global__ void moefinal_k(const float* __restrict__ part, const float* __restrict__ fused,
                           const float* __restrict__ wsc, const float* __restrict__ e_b2,
                           float* __restrict__ res)
{
    const int idx = blockIdx.x * blockDim.x + threadIdx.x;
    if (idx >= B_ * H_) return;
    const int b = idx >> 10;
    const int h = idx & (H_ - 1);
    float acc = fused[idx];
#pragma unroll 8
    for (int z = 0; z < 48; ++z) acc += part[(long)z * (B_ * H_) + idx];
    float ba = 0.f;
#pragma unroll
    for (int ge = 0; ge < GE_; ++ge) ba += wsc[b * GE_ + ge] * e_b2[ge * H_ + h];
    res[idx] = acc + ba;
}

// ===================== entry =====================
extern "C" void kernel_launch(void* const* d_in, const int* in_sizes, int n_in,
                              void* d_out, int out_size, void* d_ws, size_t ws_size,
                              hipStream_t stream)
{
    const float* h_sent  = (const float*)d_in[0];
    const float* h_term  = (const float*)d_in[1];
    const float* ts_in_w = (const float*)d_in[2];
    const float* ts_out_w= (const float*)d_in[3];
    const float* st_in_w = (const float*)d_in[4];
    const float* st_out_w= (const float*)d_in[5];
    const float* ca_in_w = (const float*)d_in[6];
    const float* ca_out_w= (const float*)d_in[7];
    const float* opq_w   = (const float*)d_in[8];
    const float* fuse_w  = (const float*)d_in[9];
    const float* gate_w  = (const float*)d_in[10];
    const float* bs_w    = (const float*)d_in[11];
    const float* bt_w    = (const float*)d_in[12];
    const float* bo_w    = (const float*)d_in[13];
    const float* cond_w  = (const float*)d_in[14];
    const float* gr_w    = (const float*)d_in[15];
    const float* er_w    = (const float*)d_in[16];
    const float* e_w1    = (const float*)d_in[17];
    const float* e_w2    = (const float*)d_in[18];
    const float* cls_w   = (const float*)d_in[19];
    const float* ts_in_b = (const float*)d_in[20];
    const float* ts_out_b= (const float*)d_in[21];
    const float* st_in_b = (const float*)d_in[22];
    const float* st_out_b= (const float*)d_in[23];
    const float* ca_in_b = (const float*)d_in[24];
    const float* ca_out_b= (const float*)d_in[25];
    const float* fuse_b  = (const float*)d_in[26];
    const float* gate_b  = (const float*)d_in[27];
    const float* bs_b    = (const float*)d_in[28];
    const float* bt_b    = (const float*)d_in[29];
    const float* bo_b    = (const float*)d_in[30];
    const float* cond_b  = (const float*)d_in[31];
    const float* gr_b    = (const float*)d_in[32];
    const float* er_b    = (const float*)d_in[33];
    const float* e_b1    = (const float*)d_in[34];
    const float* e_b2    = (const float*)d_in[35];
    const float* cls_b   = (const float*)d_in[36];
    const float* ln_b    = (const float*)d_in[37];
    const float* ln_g    = (const float*)d_in[38];
    (void)in_sizes; (void)n_in; (void)out_size; (void)ws_size;

    float* ws = (float*)d_ws;
    size_t off = 0;
    auto allocF = [&](size_t n) { float* p = ws + off; off += (n + 63) & ~(size_t)63; return p; };

    float* QALL  = allocF(16777216);
    float* WCAT  = allocF(4194304);
    float* BCAT  = allocF(4096);
    float* BKCAT = allocF(3072);
    float* wT3   = allocF(3145728);
    float* opqT  = allocF(1048576);
    float* WVCAT = allocF(2097152);
    float* WVB   = allocF(2048);
    float* WOCAT = allocF(3145728);
    float* WOB   = allocF(3072);
    float* OFFS3 = allocF(98304);
    float* SC3   = allocF(25165824);
    float* PBAR3 = allocF(1048576);
    float* CTXB3 = allocF(4194304);
    float* PARTC = allocF(16777216);
    float* OBAR3 = allocF(786432);
    float* VOUT3 = allocF(786432);
    float* ATTM  = allocF(32768);
    float* CAT3  = allocF(786432);
    float* LNC   = allocF(786432);
    float* FLIN  = allocF(262144);
    float* GATE  = allocF(262144);
    float* BSV   = allocF(65536);
    float* BTV   = allocF(65536);
    float* PROD  = allocF(65536);
    float* BIL   = allocF(262144);
    float* FUSED = allocF(262144);
    float* FUSEDH= allocF(131072);
    float* CATFV = allocF(524288);
    float* COND  = allocF(262144);
    float* GLOG  = allocF(1024);
    float* GP    = allocF(1024);
    float* ELOG  = allocF(8192);
    float* RES   = allocF(262144);
    float* PARTF = allocF(1048576);
    float* H1Wf  = allocF(12582912);
    float* PART  = allocF(12582912);
    __bf16* FUSEDbf = (__bf16*)FUSEDH;
    __bf16* H1W     = (__bf16*)H1Wf;
    float* VTERM = VOUT3;
    float* VOP   = VOUT3 + 262144;
    float* VSENT = VOUT3 + 524288;

    hipStream_t s = stream;
    const float rscale = 0.08838834764831845f;

    // ---------- precompute (merged) ----------
    cpy8_k<<<dim3(8 * 1024), dim3(256), 0, s>>>(
        ts_in_w, st_in_w + 1048576, st_in_w + 2097152, ts_in_w + 2097152,
        ca_in_w + 2097152, ts_out_w, ca_out_w, st_out_w,
        WCAT, WCAT + 2097152, WCAT + 3145728, WVCAT,
        WVCAT + 1048576, WOCAT, WOCAT + 1048576, WOCAT + 2097152);
    biascat_k<<<dim3(4), dim3(256), 0, s>>>(ts_in_b, ca_in_b, st_in_b,
                                            ts_out_b, ca_out_b, st_out_b,
                                            BCAT, BKCAT, WVB, WOB);
    tT4_k<<<dim3(32, 128), dim3(256), 0, s>>>(
        ts_in_w + 1048576, ca_in_w + 1048576, st_in_w, opq_w,
        wT3, wT3 + 1048576, wT3 + 2097152, opqT);

    // Wcomb_ca = Wq_ca @ opq_w
    sg2(s, 0, ca_in_w, opqT, nullptr, nullptr, WCAT + 1048576,
        8, 8, 1, 1024, 12, 0, 0, 1024, 0, 0, 1024, 0, 0, 0, 0,
        0, 1024, 0, 0, 0, 0, 1.f);

    // QALL
    sg2(s, 0, h_term, WCAT, BCAT, nullptr, QALL,
        32, 32, 1, 1024, 12, 0, 0, 1024, 0, 0, 1024, 0, 0, 0, 0,
        0, 4096, 0, 0, 0, 0, 1.f);

    headdot3_k<<<dim3(384), dim3(256), 0, s>>>(QALL, BKCAT, OFFS3);

    // FUSED A-fold + scores
    fsc_k<<<dim3(1, 1, 1024), dim3(512), 0, s>>>(QALL, wT3, h_sent, OFFS3, SC3, rscale);

    // fused softmax + pool
    softpb_k<<<dim3(3 * B_ * NH_), dim3(64), 0, s>>>(SC3, PBAR3, ATTM);

    // ctx weighted sum (s-split x4) + reduce
    ctxw2_k<<<dim3(B_, 4), dim3(256), 0, s>>>(PBAR3, h_sent, PARTC);
    kred_k<0><<<dim3(4194304 / 256), dim3(256), 0, s>>>(PARTC, nullptr, CTXB3,
                                                        4194304, 4194304, 4, 0);
    // ctx V-proj z=16
    sg2(s, 0, CTXB3, WVCAT, WVB, nullptr, OBAR3,
        1, 2, 16, 1024, 12, 3,
        0, 8192, 2097152, 1024,
        1024, 1048576, 131072, 1024, 128,
        0, 1024, 262144, 128, 0, 0, 1.f);

    // st path
    ohead2_k<<<dim3((B_ * H_ + 255) / 256), dim3(256), 0, s>>>(ATTM, QALL, OBAR3 + 524288);

    // out-proj z=3
    sg2(s, 0, OBAR3, WOCAT, WOB, nullptr, VOUT3,
        8, 2, 3, 1024, 12, 0,
        0, 1024, 262144, 0,
        1024, 1048576, 0, 1024, 0,
        0, 1024, 262144, 0, 0, 0, 1.f);

    // ---------- fusion head ----------
    cat3_k<<<dim3((B_ * 3 * H_ + 255) / 256), dim3(256), 0, s>>>(VSENT, VTERM, VOP, CAT3);
    ln_k<<<dim3(B_), dim3(256), 0, s>>>(CAT3, ln_g, ln_b, LNC);
    sg2(s, 0, LNC, fuse_w, nullptr, nullptr, PARTF,
        8, 2, 4, 768, 12, 2, 0, 3072, 0, 768, 3072, 0, 768, 0, 0,
        0, 1024, 0, 262144, 0, 0, 1.f);
    kred_k<0><<<dim3(1024), dim3(256), 0, s>>>(PARTF, fuse_b, FLIN, 262144, 262144, 4, 1023);
    sg2(s, 0, CAT3, gate_w, nullptr, nullptr, PARTF,
        8, 2, 4, 768, 12, 2, 0, 3072, 0, 768, 3072, 0, 768, 0, 0,
        0, 1024, 0, 262144, 0, 0, 1.f);
    kred_k<2><<<dim3(1024), dim3(256), 0, s>>>(PARTF, gate_b, GATE, 262144, 262144, 4, 1023);
    sg2(s, 0, VSENT, bs_w, nullptr, nullptr, PARTF,
        2, 2, 4, 256, 12, 2, 0, 1024, 0, 256, 1024, 0, 256, 0, 0,
        0, 256, 0, 65536, 0, 0, 1.f);
    kred_k<0><<<dim3(256), dim3(256), 0, s>>>(PARTF, bs_b, BSV, 65536, 65536, 4, 255);
    sg2(s, 0, VTERM, bt_w, nullptr, nullptr, PARTF,
        2, 2, 4, 256, 12, 2, 0, 1024, 0, 256, 1024, 0, 256, 0, 0,
        0, 256, 0, 65536, 0, 0, 1.f);
    kred_k<0><<<dim3(256), dim3(256), 0, s>>>(PARTF, bt_b, BTV, 65536, 65536, 4, 255);
    mulf_k<<<dim3((B_ * R_ + 255) / 256), dim3(256), 0, s>>>(BSV, BTV, PROD, B_ * R_);
    sg2(s, 0, PROD, bo_w, nullptr, nullptr, PARTF,
        8, 2, 2, 128, 12, 1, 0, 256, 0, 128, 256, 0, 128, 0, 0,
        0, 1024, 0, 262144, 0, 0, 1.f);
    kred_k<0><<<dim3(1024), dim3(256), 0, s>>>(PARTF, bo_b, BIL, 262144, 262144, 2, 1023);
    fuse_k<<<dim3((B_ * H_ + 255) / 256), dim3(256), 0, s>>>(GATE, FLIN, BIL, FUSED, FUSEDbf);
    catfv_k<<<dim3((B_ * 2 * H_ + 255) / 256), dim3(256), 0, s>>>(FUSED, VTERM, CATFV);
    sg2(s, 0, CATFV, cond_w, nullptr, nullptr, PARTF,
        8, 2, 4, 512, 12, 2, 0, 2048, 0, 512, 2048, 0, 512, 0, 0,
        0, 1024, 0, 262144, 0, 0, 1.f);
    kred_k<0><<<dim3(1024), dim3(256), 0, s>>>(PARTF, cond_b, COND, 262144, 262144, 4, 1023);

    // ---------- routing (per-wave dot kernels) ----------
    dotk_k<<<dim3(192), dim3(256), 0, s>>>(FUSED, gr_w, gr_b, GLOG, B_ * G_, G_, H_);
    route_k<<<dim3(1), dim3(256), 0, s>>>(GLOG, GP);
    dotk_k<<<dim3(1536), dim3(256), 0, s>>>(COND, er_w, er_b, ELOG, B_ * GE_, GE_, H_);
    epsm_k<<<dim3(3), dim3(256), 0, s>>>(ELOG, GP);

    // ---------- MoE ----------
    sgemm256_k<1, 1, 1, 1, 1><<<dim3(I_ / 128, 1, GE_), dim3(512), 0, s>>>(
        FUSEDbf, e_w1, e_b1, ELOG, nullptr, H1W,
        1024, H_, 0, H_, (long)I_ * H_, 0, 0, I_,
        (long)GE_ * I_, I_, GE_, 1.f);
    sgemm256_k<1, 1, 0, 0, 0><<<dim3(H_ / 128, 1, 2 * GE_), dim3(512), 0, s>>>(
        H1W, e_w2, nullptr, nullptr, PART, nullptr,
        2048, (long)GE_ * I_, 2048, I_, (long)H_ * I_, 2048, 1, 0,
        H_, (long)B_ * H_, 0, 1.f);
    moefinal_k<<<dim3(B_ * H_ / 256), dim3(256), 0, s>>>(PART, FUSED, ELOG, e_b2, RES);

    // ---------- classifier ----------
    dotk_k<<<dim3(192), dim3(256), 0, s>>>(RES, cls_w, cls_b, (float*)d_out, B_ * L_, L_, H_);
}

// Round 12
// 1422.962 us; speedup vs baseline: 1.7695x; 1.2397x over previous
//
#include <hip/hip_runtime.h>
#include <math.h>

// ---------------------------------------------------------------------------
// HAGMoE — round 12: revert fsc fusion (latency-bound: 867us @ 530 GB/s,
// 144 block-wide barriers, no W-prefetch). Back to the proven two-kernel
// A-fold + scores sgemm2 pipeline (~500us combined @2.8 TB/s), keeping R11's
// wins: per-wave dot kernels for tiny-N GEMMs, fused softmax/pool, merged
// setup, prefetched GEMMs. Precision tiers unchanged.
// ---------------------------------------------------------------------------

#define B_    256
#define S_    256
#define T_    16
#define H_    1024
#define NH_   8
#define DH_   128
#define M128_ 128
#define G_    3
#define E_    8
#define I_    4096
#define R_    256
#define L_    3
#define GE_   24

using bf16x8 = __attribute__((ext_vector_type(8))) __bf16;
using f32x4  = __attribute__((ext_vector_type(4))) float;

__device__ inline float wave_sum(float v) {
    for (int o = 32; o > 0; o >>= 1) v += __shfl_xor(v, o);
    return v;
}
__device__ inline float wave_max(float v) {
    for (int o = 32; o > 0; o >>= 1) v = fmaxf(v, __shfl_xor(v, o));
    return v;
}

__device__ inline void split8(const float4& f0, const float4& f1, bf16x8& hi, bf16x8& lo)
{
    const float fv[8] = {f0.x, f0.y, f0.z, f0.w, f1.x, f1.y, f1.z, f1.w};
#pragma unroll
    for (int j = 0; j < 8; ++j) {
        const __bf16 h = (__bf16)fv[j];
        hi[j] = h; lo[j] = (__bf16)(fv[j] - (float)h);
    }
}

// ===================== split-bf16 MFMA GEMM, 128x128, prefetched =============
template <int ACT>
__global__ __launch_bounds__(256) void sgemm2_k(
    const float* __restrict__ Ap, const float* __restrict__ Bp,
    const float* __restrict__ biasp, const float* __restrict__ roffp,
    float* __restrict__ Cf,
    int K, int m2shift, int zshift,
    long sA1, long sA2, long sAz1, long sAz2,
    long ldb, long sBz1, long sBz2, long sBia1, long sBia2,
    long sC1, long sC2, long sCz1, long sCz2, long sR1, long sR2,
    float scale)
{
    const int z  = blockIdx.z;
    const int z1 = z >> zshift;
    const int z2 = z & ((1 << zshift) - 1);
    const int m2mask = (1 << m2shift) - 1;
    const int row0 = blockIdx.y * 128;
    const int col0 = blockIdx.x * 128;
    const float* Ab = Ap + (long)z1 * sAz1 + (long)z2 * sAz2;
    const float* Bb = Bp + (long)z1 * sBz1 + (long)z2 * sBz2;
    const float* biasb = biasp ? biasp + (long)z1 * sBia1 + (long)z2 * sBia2 : nullptr;
    const float* roffb = roffp ? roffp + (long)z1 * sR1 + (long)z2 * sR2 : nullptr;

    __shared__ __bf16 Ahs[128 * 40];
    __shared__ __bf16 Als[128 * 40];
    __shared__ __bf16 Bhs[128 * 40];
    __shared__ __bf16 Bls[128 * 40];

    const int tid  = threadIdx.x;
    const int lane = tid & 63;
    const int wid  = tid >> 6;
    const int wm = (wid >> 1) * 64;
    const int wn = (wid & 1) * 64;
    const int fr  = lane & 15;
    const int fkb = (lane >> 4) * 16;
    const int qrow = tid >> 2;
    const int c4   = tid & 3;

    f32x4 acc[4][4] = {};
    float4 pfa[2][2], pfb[2][2];

    auto loadAB = [&](int k0) {
#pragma unroll
        for (int rep = 0; rep < 2; ++rep) {
            const int row = qrow + rep * 64;
            const int r = row0 + row;
            const int r1 = r >> m2shift, r2 = r & m2mask;
            const float* srcA = Ab + (long)r1 * sA1 + (long)r2 * sA2 + k0 + c4 * 8;
            pfa[rep][0] = *(const float4*)srcA;
            pfa[rep][1] = *(const float4*)(srcA + 4);
            const float* srcB = Bb + (long)(col0 + row) * ldb + k0 + c4 * 8;
            pfb[rep][0] = *(const float4*)srcB;
            pfb[rep][1] = *(const float4*)(srcB + 4);
        }
    };

    loadAB(0);
    for (int k0 = 0; k0 < K; k0 += 32) {
        __syncthreads();
#pragma unroll
        for (int rep = 0; rep < 2; ++rep) {
            const int row = qrow + rep * 64;
            bf16x8 hi, lo;
            split8(pfa[rep][0], pfa[rep][1], hi, lo);
            *(bf16x8*)&Ahs[row * 40 + c4 * 8] = hi;
            *(bf16x8*)&Als[row * 40 + c4 * 8] = lo;
            split8(pfb[rep][0], pfb[rep][1], hi, lo);
            *(bf16x8*)&Bhs[row * 40 + c4 * 8] = hi;
            *(bf16x8*)&Bls[row * 40 + c4 * 8] = lo;
        }
        __syncthreads();
        if (k0 + 32 < K) loadAB(k0 + 32);

        bf16x8 bh4[4], bl4[4];
#pragma unroll
        for (int n = 0; n < 4; ++n) {
            bh4[n] = *(const bf16x8*)((const char*)&Bhs[(wn + n * 16 + fr) * 40] + fkb);
            bl4[n] = *(const bf16x8*)((const char*)&Bls[(wn + n * 16 + fr) * 40] + fkb);
        }
#pragma unroll
        for (int m = 0; m < 4; ++m) {
            const bf16x8 ah = *(const bf16x8*)((const char*)&Ahs[(wm + m * 16 + fr) * 40] + fkb);
            const bf16x8 al = *(const bf16x8*)((const char*)&Als[(wm + m * 16 + fr) * 40] + fkb);
#pragma unroll
            for (int n = 0; n < 4; ++n) {
                acc[m][n] = __builtin_amdgcn_mfma_f32_16x16x32_bf16(ah, bh4[n], acc[m][n], 0, 0, 0);
                acc[m][n] = __builtin_amdgcn_mfma_f32_16x16x32_bf16(ah, bl4[n], acc[m][n], 0, 0, 0);
                acc[m][n] = __builtin_amdgcn_mfma_f32_16x16x32_bf16(al, bh4[n], acc[m][n], 0, 0, 0);
            }
        }
    }

    float* Cfb = Cf + (long)z1 * sCz1 + (long)z2 * sCz2;
    const int lr4 = (lane >> 4) * 4;
#pragma unroll
    for (int m = 0; m < 4; ++m) {
#pragma unroll
        for (int r = 0; r < 4; ++r) {
            const int rr = row0 + wm + m * 16 + lr4 + r;
            const int r1 = rr >> m2shift, r2 = rr & m2mask;
            const float ro = roffb ? roffb[rr] : 0.f;
            const long cb = (long)r1 * sC1 + (long)r2 * sC2;
#pragma unroll
            for (int n = 0; n < 4; ++n) {
                const int cc = col0 + wn + n * 16 + fr;
                float v = (acc[m][n][r] + ro) * scale;
                if (biasp) v += biasb[cc];
                if (ACT == 2) v = 1.0f / (1.0f + expf(-v));
                Cfb[cb + cc] = v;
            }
        }
    }
}

static void sg2(hipStream_t s, int act,
                const float* A, const float* B, const float* bias, const float* roff,
                float* C, int gx, int gy, int gz,
                int K, int m2shift, int zshift,
                long sA1, long sA2, long sAz1, long sAz2,
                long ldb, long sBz1, long sBz2, long sBia1, long sBia2,
                long sC1, long sC2, long sCz1, long sCz2, long sR1, long sR2,
                float scale)
{
    dim3 g(gx, gy, gz), b(256);
#define S2ARGS A, B, bias, roff, C, K, m2shift, zshift, sA1, sA2, sAz1, sAz2, \
               ldb, sBz1, sBz2, sBia1, sBia2, sC1, sC2, sCz1, sCz2, sR1, sR2, scale
    if (act == 2) sgemm2_k<2><<<g, b, 0, s>>>(S2ARGS);
    else          sgemm2_k<0><<<g, b, 0, s>>>(S2ARGS);
#undef S2ARGS
}

// ===================== 256x128 MFMA GEMM (MoE), prefetched =====================
template <int ABF16, int BSING, int ACT, int WMUL, int OUTH>
__global__ __launch_bounds__(512) void sgemm256_k(
    const void* __restrict__ Ap, const float* __restrict__ Bp,
    const float* __restrict__ biasp, const float* __restrict__ wmulp,
    float* __restrict__ Cf, __bf16* __restrict__ Ch,
    int K, long sA1, long sAz, long ldb, long sBz, long sBz2, int bzshift,
    long sBias, long sC1, long sCz, long sWr, float scale)
{
    const int z    = blockIdx.z;
    const int col0 = blockIdx.x * 128;
    const int z1 = z >> bzshift;
    const int z2 = z - (z1 << bzshift);
    const float* Bb = Bp + (long)z1 * sBz + (long)z2 * sBz2;
    const float* biasb = biasp ? biasp + (long)z1 * sBias : nullptr;

    __shared__ __bf16 Ah[256 * 40];
    __shared__ __bf16 Al[ABF16 ? 64 : 256 * 40];
    __shared__ __bf16 Bh[128 * 40];
    __shared__ __bf16 Bl[BSING ? 64 : 128 * 40];

    const int tid  = threadIdx.x;
    const int lane = tid & 63;
    const int wid  = tid >> 6;
    const int wm = (wid >> 1) * 64;
    const int wn = (wid & 1) * 64;
    const int fr  = lane & 15;
    const int fkb = (lane >> 4) * 16;

    f32x4 acc[4][4] = {};
    bf16x8 pfah[2];
    float4 pfaf[2][2];
    float4 pfb[2];

    auto loadAB = [&](int k0) {
#pragma unroll
        for (int rep = 0; rep < 2; ++rep) {
            const int idx = tid + rep * 512;
            const int row = idx >> 2;
            const int cc4 = idx & 3;
            if (ABF16) {
                pfah[rep] = *(const bf16x8*)((const __bf16*)Ap + (long)z * sAz +
                                             (long)row * sA1 + k0 + cc4 * 8);
            } else {
                const float* src = (const float*)Ap + (long)z * sAz +
                                   (long)row * sA1 + k0 + cc4 * 8;
                pfaf[rep][0] = *(const float4*)src;
                pfaf[rep][1] = *(const float4*)(src + 4);
            }
        }
        {
            const int row = tid >> 2;
            const int cc4 = tid & 3;
            const float* src = Bb + (long)(col0 + row) * ldb + k0 + cc4 * 8;
            pfb[0] = *(const float4*)src;
            pfb[1] = *(const float4*)(src + 4);
        }
    };

    loadAB(0);
    for (int k0 = 0; k0 < K; k0 += 32) {
        __syncthreads();
#pragma unroll
        for (int rep = 0; rep < 2; ++rep) {
            const int idx = tid + rep * 512;
            const int row = idx >> 2;
            const int cc4 = idx & 3;
            if (ABF16) {
                *(bf16x8*)&Ah[row * 40 + cc4 * 8] = pfah[rep];
            } else {
                bf16x8 hi, lo;
                split8(pfaf[rep][0], pfaf[rep][1], hi, lo);
                *(bf16x8*)&Ah[row * 40 + cc4 * 8] = hi;
                *(bf16x8*)&Al[row * 40 + cc4 * 8] = lo;
            }
        }
        {
            const int row = tid >> 2;
            const int cc4 = tid & 3;
            bf16x8 hi, lo;
            split8(pfb[0], pfb[1], hi, lo);
            *(bf16x8*)&Bh[row * 40 + cc4 * 8] = hi;
            if (!BSING) *(bf16x8*)&Bl[row * 40 + cc4 * 8] = lo;
        }
        __syncthreads();
        if (k0 + 32 < K) loadAB(k0 + 32);

        bf16x8 bh4[4], bl4[4];
#pragma unroll
        for (int n = 0; n < 4; ++n) {
            bh4[n] = *(const bf16x8*)((const char*)&Bh[(wn + n * 16 + fr) * 40] + fkb);
            if (!BSING) bl4[n] = *(const bf16x8*)((const char*)&Bl[(wn + n * 16 + fr) * 40] + fkb);
        }
#pragma unroll
        for (int m = 0; m < 4; ++m) {
            const bf16x8 ah = *(const bf16x8*)((const char*)&Ah[(wm + m * 16 + fr) * 40] + fkb);
            bf16x8 al;
            if (!ABF16) al = *(const bf16x8*)((const char*)&Al[(wm + m * 16 + fr) * 40] + fkb);
#pragma unroll
            for (int n = 0; n < 4; ++n) {
                acc[m][n] = __builtin_amdgcn_mfma_f32_16x16x32_bf16(ah, bh4[n], acc[m][n], 0, 0, 0);
                if (!BSING) acc[m][n] = __builtin_amdgcn_mfma_f32_16x16x32_bf16(ah, bl4[n], acc[m][n], 0, 0, 0);
                if (!ABF16) acc[m][n] = __builtin_amdgcn_mfma_f32_16x16x32_bf16(al, bh4[n], acc[m][n], 0, 0, 0);
            }
        }
    }

    const int lr4 = (lane >> 4) * 4;
#pragma unroll
    for (int m = 0; m < 4; ++m) {
#pragma unroll
        for (int r = 0; r < 4; ++r) {
            const int rr = wm + m * 16 + lr4 + r;
#pragma unroll
            for (int n = 0; n < 4; ++n) {
                const int cc = col0 + wn + n * 16 + fr;
                float v = acc[m][n][r] * scale;
                if (biasp) v += biasb[cc];
                if (ACT == 1) v = 0.5f * v * (1.0f + erff(v * 0.70710678118654752f));
                if (WMUL) v *= wmulp[(long)rr * sWr + z];
                if (OUTH) Ch[(long)z * sCz + (long)rr * sC1 + cc] = (__bf16)v;
                else      Cf[(long)z * sCz + (long)rr * sC1 + cc] = v;
            }
        }
    }
}

// ===================== per-wave dot GEMM (tiny N) =====================
__global__ void dotk_k(const float* __restrict__ A, const float* __restrict__ Bw,
                       const float* __restrict__ bias, float* __restrict__ out,
                       int MN, int N, int K)
{
    const int idx = blockIdx.x * (blockDim.x >> 6) + (threadIdx.x >> 6);
    if (idx >= MN) return;
    const int m = idx / N, n = idx - m * N;
    const int lane = threadIdx.x & 63;
    const float* a = A + (long)m * K;
    const float* bb = Bw + (long)n * K;
    float s = 0.f;
    for (int k = lane * 4; k < K; k += 256) {
        const float4 av = *(const float4*)(a + k);
        const float4 bv = *(const float4*)(bb + k);
        s += av.x * bv.x + av.y * bv.y + av.z * bv.z + av.w * bv.w;
    }
    s = wave_sum(s);
    if (lane == 0) out[idx] = s + (bias ? bias[n] : 0.f);
}

// ===================== reduce-act =====================
template <int ACT>
__global__ void kred_k(const float* __restrict__ part, const float* __restrict__ bias,
                       float* __restrict__ out, int n, long stride, int nz, int biasMask)
{
    const int i = blockIdx.x * blockDim.x + threadIdx.x;
    if (i >= n) return;
    float v = 0.f;
    for (int z = 0; z < nz; ++z) v += part[(long)z * stride + i];
    if (bias) v += bias[i & biasMask];
    if (ACT == 2) v = 1.0f / (1.0f + expf(-v));
    out[i] = v;
}

// ===================== merged setup =====================
__global__ void cpy8_k(const float* s0, const float* s1, const float* s2, const float* s3,
                       const float* s4, const float* s5, const float* s6, const float* s7,
                       float* d0, float* d1, float* d2, float* d3,
                       float* d4, float* d5, float* d6, float* d7)
{
    const int seg = blockIdx.x >> 10;
    const int i = ((blockIdx.x & 1023) * 256 + threadIdx.x);
    const float* srcs[8] = {s0, s1, s2, s3, s4, s5, s6, s7};
    float* dsts[8] = {d0, d1, d2, d3, d4, d5, d6, d7};
    ((float4*)dsts[seg])[i] = ((const float4*)srcs[seg])[i];
}

__global__ void tT4_k(const float* s0, const float* s1, const float* s2, const float* s3,
                      float* d0, float* d1, float* d2, float* d3)
{
    __shared__ float t[32][33];
    const int seg = blockIdx.y >> 5;
    const float* src = seg == 0 ? s0 : seg == 1 ? s1 : seg == 2 ? s2 : s3;
    float* dst = seg == 0 ? d0 : seg == 1 ? d1 : seg == 2 ? d2 : d3;
    const int c0 = blockIdx.x * 32, r0 = (blockIdx.y & 31) * 32;
    const int tx = threadIdx.x & 31, ty = threadIdx.x >> 5;
#pragma unroll
    for (int i = 0; i < 4; ++i) {
        const int r = ty + i * 8;
        t[r][tx] = src[(long)(r0 + r) * 1024 + c0 + tx];
    }
    __syncthreads();
#pragma unroll
    for (int i = 0; i < 4; ++i) {
        const int r = ty + i * 8;
        dst[(long)(c0 + r) * 1024 + r0 + tx] = t[tx][r];
    }
}

__global__ void biascat_k(const float* __restrict__ ts_b, const float* __restrict__ ca_b,
                          const float* __restrict__ st_b,
                          const float* __restrict__ ts_ob, const float* __restrict__ ca_ob,
                          const float* __restrict__ st_ob,
                          float* __restrict__ BCAT, float* __restrict__ BKCAT,
                          float* __restrict__ WVB, float* __restrict__ WOB)
{
    const int i = blockIdx.x * blockDim.x + threadIdx.x;
    if (i >= 1024) return;
    BCAT[i] = ts_b[i]; BCAT[1024 + i] = ca_b[i];
    BCAT[2048 + i] = st_b[1024 + i]; BCAT[3072 + i] = st_b[2048 + i];
    BKCAT[i] = ts_b[1024 + i]; BKCAT[1024 + i] = ca_b[1024 + i]; BKCAT[2048 + i] = st_b[i];
    WVB[i] = ts_b[2048 + i]; WVB[1024 + i] = ca_b[2048 + i];
    WOB[i] = ts_ob[i]; WOB[1024 + i] = ca_ob[i]; WOB[2048 + i] = st_ob[i];
}

// ===================== glue kernels =====================
__global__ void headdot3_k(const float* __restrict__ QALL, const float* __restrict__ BKCAT,
                           float* __restrict__ out)
{
    const int idx = blockIdx.x * blockDim.x + threadIdx.x;
    if (idx >= 3 * B_ * T_ * NH_) return;
    const int mod = idx >> 15;
    const int b = (idx >> 7) & 255;
    const int t = (idx >> 3) & 15;
    const int h = idx & 7;
    const float* q = QALL + (long)(b * 16 + t) * 4096 + mod * 1024 + h * 128;
    const float* bb = BKCAT + mod * 1024 + h * 128;
    float sum = 0.f;
    for (int k = 0; k < DH_; ++k) sum += q[k] * bb[k];
    out[idx] = sum;
}

__global__ __launch_bounds__(64) void softpb_k(const float* __restrict__ sc3,
                                               float* __restrict__ pbar,
                                               float* __restrict__ attm)
{
    const int blk = blockIdx.x;
    const int h = blk & 7;
    const int b = (blk >> 3) & 255;
    const int mod = blk >> 11;
    const int lane = threadIdx.x;
    const float* base = sc3 + (long)mod * 8388608 + (long)b * 32768 + (long)h * 256;
    float v[16][4];
#pragma unroll
    for (int t = 0; t < 16; ++t) {
        const float* rowp = base + (long)t * 2048;
#pragma unroll
        for (int j = 0; j < 4; ++j) v[t][j] = rowp[j * 64 + lane];
    }
    if (mod < 2) {
        float pb[4] = {0.f, 0.f, 0.f, 0.f};
#pragma unroll
        for (int t = 0; t < 16; ++t) {
            float m = fmaxf(fmaxf(v[t][0], v[t][1]), fmaxf(v[t][2], v[t][3]));
            m = wave_max(m);
            const float e0 = expf(v[t][0] - m), e1 = expf(v[t][1] - m);
            const float e2 = expf(v[t][2] - m), e3 = expf(v[t][3] - m);
            const float inv = 1.f / wave_sum(e0 + e1 + e2 + e3);
            pb[0] += e0 * inv; pb[1] += e1 * inv; pb[2] += e2 * inv; pb[3] += e3 * inv;
        }
        float* pd = pbar + (long)mod * 524288 + (long)b * 2048 + h * 256;
#pragma unroll
        for (int j = 0; j < 4; ++j) pd[j * 64 + lane] = pb[j] * (1.0f / 16.f);
    } else {
        float am[16];
#pragma unroll
        for (int t = 0; t < 16; ++t) am[t] = 0.f;
#pragma unroll
        for (int j = 0; j < 4; ++j) {
            float mx = v[0][j];
#pragma unroll
            for (int t = 1; t < 16; ++t) mx = fmaxf(mx, v[t][j]);
            float e[16];
            float sum = 0.f;
#pragma unroll
            for (int t = 0; t < 16; ++t) { e[t] = expf(v[t][j] - mx); sum += e[t]; }
            const float inv = 1.f / sum;
#pragma unroll
            for (int t = 0; t < 16; ++t) am[t] += e[t] * inv;
        }
#pragma unroll
        for (int t = 0; t < 16; ++t) {
            const float sm = wave_sum(am[t]) * (1.0f / 256.f);
            if (lane == 0) attm[b * 128 + t * 8 + h] = sm;
        }
    }
}

__global__ __launch_bounds__(256) void ctxw2_k(const float* __restrict__ pbar,
                                               const float* __restrict__ hs,
                                               float* __restrict__ part)
{
    const int b = blockIdx.x;
    const int sc = blockIdx.y;
    __shared__ float pl[16][64];
    const int tid = threadIdx.x;
    for (int i = tid; i < 16 * 64; i += 256) {
        const int row = i >> 6;
        const int mod = row >> 3;
        pl[row][i & 63] = pbar[(long)mod * 524288 + (long)b * 2048 +
                               (row & 7) * 256 + sc * 64 + (i & 63)];
    }
    __syncthreads();
    const int k0 = tid * 4;
    float4 acc[16] = {};
    const float* hb = hs + (long)b * S_ * H_ + (long)sc * 64 * H_;
    for (int s = 0; s < 64; ++s) {
        const float4 vv = *(const float4*)(hb + (long)s * H_ + k0);
#pragma unroll
        for (int j = 0; j < 16; ++j) {
            const float p = pl[j][s];
            acc[j].x += p * vv.x; acc[j].y += p * vv.y;
            acc[j].z += p * vv.z; acc[j].w += p * vv.w;
        }
    }
    float* ob = part + (long)sc * 4194304;
#pragma unroll
    for (int j = 0; j < 16; ++j) {
        const int mod = j >> 3, hh = j & 7;
        *(float4*)(ob + (long)mod * 2097152 + (long)b * 8192 + hh * 1024 + k0) = acc[j];
    }
}

__global__ void ohead2_k(const float* __restrict__ attm, const float* __restrict__ QALL,
                         float* __restrict__ outb)
{
    const int idx = blockIdx.x * blockDim.x + threadIdx.x;
    if (idx >= B_ * H_) return;
    const int c = idx & (H_ - 1);
    const int b = idx >> 10;
    float sv = 0.f;
#pragma unroll
    for (int t = 0; t < T_; ++t)
        sv += attm[b * M128_ + t * NH_ + (c >> 7)] * QALL[(long)(b * 16 + t) * 4096 + 3072 + c];
    outb[idx] = sv;
}

__global__ void cat3_k(const float* __restrict__ vs, const float* __restrict__ vt,
                       const float* __restrict__ vo, float* __restrict__ out)
{
    const int idx = blockIdx.x * blockDim.x + threadIdx.x;
    if (idx >= B_ * 3 * H_) return;
    const int k = idx % (3 * H_);
    const int b = idx / (3 * H_);
    float v;
    if (k < H_)          v = vs[b * H_ + k];
    else if (k < 2 * H_) v = vt[b * H_ + k - H_];
    else                 v = vo[b * H_ + k - 2 * H_];
    out[idx] = v;
}

__global__ void ln_k(const float* __restrict__ cat3, const float* __restrict__ g,
                     const float* __restrict__ bta, float* __restrict__ out)
{
    const int b = blockIdx.x;
    const int tid = threadIdx.x;
    __shared__ float buf[3 * H_];
    __shared__ float red[4];
    const float* src = cat3 + (long)b * 3 * H_;
    float sv = 0.f;
    for (int i = tid; i < 3 * H_; i += 256) { const float x = src[i]; buf[i] = x; sv += x; }
    sv = wave_sum(sv);
    if ((tid & 63) == 0) red[tid >> 6] = sv;
    __syncthreads();
    const float mu = (red[0] + red[1] + red[2] + red[3]) * (1.f / (3 * H_));
    __syncthreads();
    float s2 = 0.f;
    for (int i = tid; i < 3 * H_; i += 256) { const float d0 = buf[i] - mu; s2 += d0 * d0; }
    s2 = wave_sum(s2);
    if ((tid & 63) == 0) red[tid >> 6] = s2;
    __syncthreads();
    const float var = (red[0] + red[1] + red[2] + red[3]) * (1.f / (3 * H_));
    const float rstd = rsqrtf(var + 1e-5f);
    float* dst = out + (long)b * 3 * H_;
    for (int i = tid; i < 3 * H_; i += 256)
        dst[i] = (buf[i] - mu) * rstd * g[i] + bta[i];
}

__global__ void mulf_k(const float* __restrict__ a, const float* __restrict__ b2,
                       float* __restrict__ out, int n)
{
    const int idx = blockIdx.x * blockDim.x + threadIdx.x;
    if (idx < n) out[idx] = a[idx] * b2[idx];
}

__global__ void fuse_k(const float* __restrict__ g, const float* __restrict__ flin,
                       const float* __restrict__ bil, float* __restrict__ fused,
                       __bf16* __restrict__ fusedh)
{
    const int idx = blockIdx.x * blockDim.x + threadIdx.x;
    if (idx >= B_ * H_) return;
    const float gg = g[idx];
    const float v = gg * flin[idx] + (1.f - gg) * bil[idx];
    fused[idx] = v;
    fusedh[idx] = (__bf16)v;
}

__global__ void catfv_k(const float* __restrict__ fused, const float* __restrict__ vt,
                        float* __restrict__ out)
{
    const int idx = blockIdx.x * blockDim.x + threadIdx.x;
    if (idx >= B_ * 2 * H_) return;
    const int k = idx % (2 * H_);
    const int b = idx / (2 * H_);
    out[idx] = (k < H_) ? fused[b * H_ + k] : vt[b * H_ + k - H_];
}

__global__ void route_k(const float* __restrict__ glog, float* __restrict__ gp)
{
    const int b = blockIdx.x * blockDim.x + threadIdx.x;
    if (b >= B_) return;
    const float x0 = glog[b * 3], x1 = glog[b * 3 + 1], x2 = glog[b * 3 + 2];
    const float m1 = fmaxf(x0, fmaxf(x1, x2));
    float thr;
    if (x0 == m1)      thr = fmaxf(x1, x2);
    else if (x1 == m1) thr = fmaxf(x0, x2);
    else               thr = fmaxf(x0, x1);
    const float y0 = (x0 >= thr) ? x0 : -1e9f;
    const float y1 = (x1 >= thr) ? x1 : -1e9f;
    const float y2 = (x2 >= thr) ? x2 : -1e9f;
    const float mm = fmaxf(y0, fmaxf(y1, y2));
    const float e0 = expf(y0 - mm), e1 = expf(y1 - mm), e2 = expf(y2 - mm);
    const float inv = 1.f / (e0 + e1 + e2);
    gp[b * 3] = e0 * inv; gp[b * 3 + 1] = e1 * inv; gp[b * 3 + 2] = e2 * inv;
}

__global__ void epsm_k(float* __restrict__ elog, const float* __restrict__ gp)
{
    const int idx = blockIdx.x * blockDim.x + threadIdx.x;
    if (idx >= B_ * G_) return;
    float* p = elog + (long)idx * E_;
    float m = p[0];
#pragma unroll
    for (int e = 1; e < E_; ++e) m = fmaxf(m, p[e]);
    float sum = 0.f;
    float v[E_];
#pragma unroll
    for (int e = 0; e < E_; ++e) { v[e] = expf(p[e] - m); sum += v[e]; }
    const float w = gp[idx] / sum;
#pragma unroll
    for (int e = 0; e < E_; ++e) p[e] = v[e] * w;
}

__global__ void moefinal_k(const float* __restrict__ part, const float* __restrict__ fused,
                           const float* __restrict__ wsc, const float* __restrict__ e_b2,
                           float* __restrict__ res)
{
    const int idx = blockIdx.x * blockDim.x + threadIdx.x;
    if (idx >= B_ * H_) return;
    const int b = idx >> 10;
    const int h = idx & (H_ - 1);
    float acc = fused[idx];
#pragma unroll 8
    for (int z = 0; z < 48; ++z) acc += part[(long)z * (B_ * H_) + idx];
    float ba = 0.f;
#pragma unroll
    for (int ge = 0; ge < GE_; ++ge) ba += wsc[b * GE_ + ge] * e_b2[ge * H_ + h];
    res[idx] = acc + ba;
}

// ===================== entry =====================
extern "C" void kernel_launch(void* const* d_in, const int* in_sizes, int n_in,
                              void* d_out, int out_size, void* d_ws, size_t ws_size,
                              hipStream_t stream)
{
    const float* h_sent  = (const float*)d_in[0];
    const float* h_term  = (const float*)d_in[1];
    const float* ts_in_w = (const float*)d_in[2];
    const float* ts_out_w= (const float*)d_in[3];
    const float* st_in_w = (const float*)d_in[4];
    const float* st_out_w= (const float*)d_in[5];
    const float* ca_in_w = (const float*)d_in[6];
    const float* ca_out_w= (const float*)d_in[7];
    const float* opq_w   = (const float*)d_in[8];
    const float* fuse_w  = (const float*)d_in[9];
    const float* gate_w  = (const float*)d_in[10];
    const float* bs_w    = (const float*)d_in[11];
    const float* bt_w    = (const float*)d_in[12];
    const float* bo_w    = (const float*)d_in[13];
    const float* cond_w  = (const float*)d_in[14];
    const float* gr_w    = (const float*)d_in[15];
    const float* er_w    = (const float*)d_in[16];
    const float* e_w1    = (const float*)d_in[17];
    const float* e_w2    = (const float*)d_in[18];
    const float* cls_w   = (const float*)d_in[19];
    const float* ts_in_b = (const float*)d_in[20];
    const float* ts_out_b= (const float*)d_in[21];
    const float* st_in_b = (const float*)d_in[22];
    const float* st_out_b= (const float*)d_in[23];
    const float* ca_in_b = (const float*)d_in[24];
    const float* ca_out_b= (const float*)d_in[25];
    const float* fuse_b  = (const float*)d_in[26];
    const float* gate_b  = (const float*)d_in[27];
    const float* bs_b    = (const float*)d_in[28];
    const float* bt_b    = (const float*)d_in[29];
    const float* bo_b    = (const float*)d_in[30];
    const float* cond_b  = (const float*)d_in[31];
    const float* gr_b    = (const float*)d_in[32];
    const float* er_b    = (const float*)d_in[33];
    const float* e_b1    = (const float*)d_in[34];
    const float* e_b2    = (const float*)d_in[35];
    const float* cls_b   = (const float*)d_in[36];
    const float* ln_b    = (const float*)d_in[37];
    const float* ln_g    = (const float*)d_in[38];
    (void)in_sizes; (void)n_in; (void)out_size; (void)ws_size;

    float* ws = (float*)d_ws;
    size_t off = 0;
    auto allocF = [&](size_t n) { float* p = ws + off; off += (n + 63) & ~(size_t)63; return p; };

    float* QALL  = allocF(16777216);
    float* WCAT  = allocF(4194304);
    float* BCAT  = allocF(4096);
    float* BKCAT = allocF(3072);
    float* wT3   = allocF(3145728);
    float* opqT  = allocF(1048576);
    float* WVCAT = allocF(2097152);
    float* WVB   = allocF(2048);
    float* WOCAT = allocF(3145728);
    float* WOB   = allocF(3072);
    float* OFFS3 = allocF(98304);
    float* BIG3  = allocF(100663296);   // [3][B][128][H]
    float* SC3   = allocF(25165824);
    float* PBAR3 = allocF(1048576);
    float* CTXB3 = allocF(4194304);
    float* PARTC = allocF(16777216);
    float* OBAR3 = allocF(786432);
    float* VOUT3 = allocF(786432);
    float* ATTM  = allocF(32768);
    float* CAT3  = allocF(786432);
    float* LNC   = allocF(786432);
    float* FLIN  = allocF(262144);
    float* GATE  = allocF(262144);
    float* BSV   = allocF(65536);
    float* BTV   = allocF(65536);
    float* PROD  = allocF(65536);
    float* BIL   = allocF(262144);
    float* FUSED = allocF(262144);
    float* FUSEDH= allocF(131072);
    float* CATFV = allocF(524288);
    float* COND  = allocF(262144);
    float* GLOG  = allocF(1024);
    float* GP    = allocF(1024);
    float* ELOG  = allocF(8192);
    float* RES   = allocF(262144);
    float* PARTF = allocF(1048576);
    float* H1Wf  = allocF(12582912);
    float* PART  = allocF(12582912);
    __bf16* FUSEDbf = (__bf16*)FUSEDH;
    __bf16* H1W     = (__bf16*)H1Wf;
    float* VTERM = VOUT3;
    float* VOP   = VOUT3 + 262144;
    float* VSENT = VOUT3 + 524288;

    hipStream_t s = stream;
    const float rscale = 0.08838834764831845f;

    // ---------- precompute (merged) ----------
    cpy8_k<<<dim3(8 * 1024), dim3(256), 0, s>>>(
        ts_in_w, st_in_w + 1048576, st_in_w + 2097152, ts_in_w + 2097152,
        ca_in_w + 2097152, ts_out_w, ca_out_w, st_out_w,
        WCAT, WCAT + 2097152, WCAT + 3145728, WVCAT,
        WVCAT + 1048576, WOCAT, WOCAT + 1048576, WOCAT + 2097152);
    biascat_k<<<dim3(4), dim3(256), 0, s>>>(ts_in_b, ca_in_b, st_in_b,
                                            ts_out_b, ca_out_b, st_out_b,
                                            BCAT, BKCAT, WVB, WOB);
    tT4_k<<<dim3(32, 128), dim3(256), 0, s>>>(
        ts_in_w + 1048576, ca_in_w + 1048576, st_in_w, opq_w,
        wT3, wT3 + 1048576, wT3 + 2097152, opqT);

    // Wcomb_ca = Wq_ca @ opq_w
    sg2(s, 0, ca_in_w, opqT, nullptr, nullptr, WCAT + 1048576,
        8, 8, 1, 1024, 12, 0, 0, 1024, 0, 0, 1024, 0, 0, 0, 0,
        0, 1024, 0, 0, 0, 0, 1.f);

    // QALL
    sg2(s, 0, h_term, WCAT, BCAT, nullptr, QALL,
        32, 32, 1, 1024, 12, 0, 0, 1024, 0, 0, 1024, 0, 0, 0, 0,
        0, 4096, 0, 0, 0, 0, 1.f);

    headdot3_k<<<dim3(384), dim3(256), 0, s>>>(QALL, BKCAT, OFFS3);

    // A-fold z=24 (mod,h): BIG3
    sg2(s, 0, QALL, wT3, nullptr, nullptr, BIG3,
        8, 32, 24, 128, 4, 3,
        65536, 4096, 1024, 128,
        1024, 1048576, 128, 0, 0,
        131072, 8192, 33554432, 1024, 0, 0, 1.f);

    // scores z=768 (mod,b): SC3
    sg2(s, 0, BIG3, h_sent, nullptr, OFFS3, SC3,
        2, 1, 768, 1024, 12, 8,
        0, 1024, 33554432, 131072,
        1024, 0, 262144, 0, 0,
        0, 256, 8388608, 32768, 32768, 128, rscale);

    // fused softmax + pool
    softpb_k<<<dim3(3 * B_ * NH_), dim3(64), 0, s>>>(SC3, PBAR3, ATTM);

    // ctx weighted sum (s-split x4) + reduce
    ctxw2_k<<<dim3(B_, 4), dim3(256), 0, s>>>(PBAR3, h_sent, PARTC);
    kred_k<0><<<dim3(4194304 / 256), dim3(256), 0, s>>>(PARTC, nullptr, CTXB3,
                                                        4194304, 4194304, 4, 0);
    // ctx V-proj z=16
    sg2(s, 0, CTXB3, WVCAT, WVB, nullptr, OBAR3,
        1, 2, 16, 1024, 12, 3,
        0, 8192, 2097152, 1024,
        1024, 1048576, 131072, 1024, 128,
        0, 1024, 262144, 128, 0, 0, 1.f);

    // st path
    ohead2_k<<<dim3((B_ * H_ + 255) / 256), dim3(256), 0, s>>>(ATTM, QALL, OBAR3 + 524288);

    // out-proj z=3
    sg2(s, 0, OBAR3, WOCAT, WOB, nullptr, VOUT3,
        8, 2, 3, 1024, 12, 0,
        0, 1024, 262144, 0,
        1024, 1048576, 0, 1024, 0,
        0, 1024, 262144, 0, 0, 0, 1.f);

    // ---------- fusion head ----------
    cat3_k<<<dim3((B_ * 3 * H_ + 255) / 256), dim3(256), 0, s>>>(VSENT, VTERM, VOP, CAT3);
    ln_k<<<dim3(B_), dim3(256), 0, s>>>(CAT3, ln_g, ln_b, LNC);
    sg2(s, 0, LNC, fuse_w, nullptr, nullptr, PARTF,
        8, 2, 4, 768, 12, 2, 0, 3072, 0, 768, 3072, 0, 768, 0, 0,
        0, 1024, 0, 262144, 0, 0, 1.f);
    kred_k<0><<<dim3(1024), dim3(256), 0, s>>>(PARTF, fuse_b, FLIN, 262144, 262144, 4, 1023);
    sg2(s, 0, CAT3, gate_w, nullptr, nullptr, PARTF,
        8, 2, 4, 768, 12, 2, 0, 3072, 0, 768, 3072, 0, 768, 0, 0,
        0, 1024, 0, 262144, 0, 0, 1.f);
    kred_k<2><<<dim3(1024), dim3(256), 0, s>>>(PARTF, gate_b, GATE, 262144, 262144, 4, 1023);
    sg2(s, 0, VSENT, bs_w, nullptr, nullptr, PARTF,
        2, 2, 4, 256, 12, 2, 0, 1024, 0, 256, 1024, 0, 256, 0, 0,
        0, 256, 0, 65536, 0, 0, 1.f);
    kred_k<0><<<dim3(256), dim3(256), 0, s>>>(PARTF, bs_b, BSV, 65536, 65536, 4, 255);
    sg2(s, 0, VTERM, bt_w, nullptr, nullptr, PARTF,
        2, 2, 4, 256, 12, 2, 0, 1024, 0, 256, 1024, 0, 256, 0, 0,
        0, 256, 0, 65536, 0, 0, 1.f);
    kred_k<0><<<dim3(256), dim3(256), 0, s>>>(PARTF, bt_b, BTV, 65536, 65536, 4, 255);
    mulf_k<<<dim3((B_ * R_ + 255) / 256), dim3(256), 0, s>>>(BSV, BTV, PROD, B_ * R_);
    sg2(s, 0, PROD, bo_w, nullptr, nullptr, PARTF,
        8, 2, 2, 128, 12, 1, 0, 256, 0, 128, 256, 0, 128, 0, 0,
        0, 1024, 0, 262144, 0, 0, 1.f);
    kred_k<0><<<dim3(1024), dim3(256), 0, s>>>(PARTF, bo_b, BIL, 262144, 262144, 2, 1023);
    fuse_k<<<dim3((B_ * H_ + 255) / 256), dim3(256), 0, s>>>(GATE, FLIN, BIL, FUSED, FUSEDbf);
    catfv_k<<<dim3((B_ * 2 * H_ + 255) / 256), dim3(256), 0, s>>>(FUSED, VTERM, CATFV);
    sg2(s, 0, CATFV, cond_w, nullptr, nullptr, PARTF,
        8, 2, 4, 512, 12, 2, 0, 2048, 0, 512, 2048, 0, 512, 0, 0,
        0, 1024, 0, 262144, 0, 0, 1.f);
    kred_k<0><<<dim3(1024), dim3(256), 0, s>>>(PARTF, cond_b, COND, 262144, 262144, 4, 1023);

    // ---------- routing (per-wave dot kernels) ----------
    dotk_k<<<dim3(192), dim3(256), 0, s>>>(FUSED, gr_w, gr_b, GLOG, B_ * G_, G_, H_);
    route_k<<<dim3(1), dim3(256), 0, s>>>(GLOG, GP);
    dotk_k<<<dim3(1536), dim3(256), 0, s>>>(COND, er_w, er_b, ELOG, B_ * GE_, GE_, H_);
    epsm_k<<<dim3(3), dim3(256), 0, s>>>(ELOG, GP);

    // ---------- MoE ----------
    sgemm256_k<1, 1, 1, 1, 1><<<dim3(I_ / 128, 1, GE_), dim3(512), 0, s>>>(
        FUSEDbf, e_w1, e_b1, ELOG, nullptr, H1W,
        1024, H_, 0, H_, (long)I_ * H_, 0, 0, I_,
        (long)GE_ * I_, I_, GE_, 1.f);
    sgemm256_k<1, 1, 0, 0, 0><<<dim3(H_ / 128, 1, 2 * GE_), dim3(512), 0, s>>>(
        H1W, e_w2, nullptr, nullptr, PART, nullptr,
        2048, (long)GE_ * I_, 2048, I_, (long)H_ * I_, 2048, 1, 0,
        H_, (long)B_ * H_, 0, 1.f);
    moefinal_k<<<dim3(B_ * H_ / 256), dim3(256), 0, s>>>(PART, FUSED, ELOG, e_b2, RES);

    // ---------- classifier ----------
    dotk_k<<<dim3(192), dim3(256), 0, s>>>(RES, cls_w, cls_b, (float*)d_out, B_ * L_, L_, H_);
}